// Round 10
// baseline (254.773 us; speedup 1.0000x reference)
//
#include <hip/hip_runtime.h>
#include <math.h>

#define NN 50000
#define NE 600000
#define HID 128
#define NG 64
#define CAP 48    // bucket capacity: Poisson(12) max-degree ~28; P(overflow)<1e-15
#define ASTRH 136 // LDS A-tile row stride in halves (272B): frag reads <=2-way

using half8v = __attribute__((ext_vector_type(8))) _Float16;
using half2v = __attribute__((ext_vector_type(2))) _Float16;
using f32x4  = __attribute__((ext_vector_type(4))) float;

// ---------------- Fused prep: pos boundaries | zero deg/gsum | weight split ----
__global__ void k_prep(const int* __restrict__ batch, int* __restrict__ deg,
                       float* __restrict__ gsum, int* __restrict__ pos,
                       const float* __restrict__ W1a, const float* __restrict__ W1b,
                       const float* __restrict__ W2a, const float* __restrict__ W2b,
                       _Float16* __restrict__ whi, _Float16* __restrict__ wlo) {
  int b = blockIdx.x, t = threadIdx.x;
  if (b < 196) {
    int i = b * 256 + t;
    if (i < NN) {
      int bb = batch[i];
      if (i == 0) {
        for (int g = 0; g <= bb; ++g) pos[g] = 0;
      } else {
        int bp = batch[i - 1];
        for (int g = bp + 1; g <= bb; ++g) pos[g] = i;
      }
      if (i == NN - 1) {
        for (int g = bb + 1; g <= NG; ++g) pos[g] = NN;
      }
    }
  } else if (b < 245) {
    int i = (b - 196) * 256 + t;
    if (i < 12500) reinterpret_cast<int4*>(deg)[i] = make_int4(0, 0, 0, 0);
    if (i < 2048) reinterpret_cast<float4*>(gsum)[i] = make_float4(0.f, 0.f, 0.f, 0.f);
  } else {
    int tid = (b - 245) * 256 + t;  // 0..8191
    int m = tid >> 11;
    const float* W = (m == 0) ? W1a : (m == 1) ? W1b : (m == 2) ? W2a : W2b;
    int rem = tid & 2047;
    int kt = rem >> 9;
    int fj = (rem >> 6) & 7;
    int l = rem & 63;
    int col = fj * 16 + (l & 15);
    int kbase = kt * 32 + (l >> 4) * 8;
    size_t obase = (size_t)m * 16384 + (size_t)(((kt * 8 + fj) * 64 + l)) * 8;
#pragma unroll
    for (int j = 0; j < 8; ++j) {
      float x = W[(size_t)(kbase + j) * HID + col];
      _Float16 h = (_Float16)x;
      whi[obase + j] = h;
      wlo[obase + j] = (_Float16)(x - (float)h);
    }
  }
}

// ---------------- One-pass bucketed CSR, 4 edges/thread ----------------
__global__ void k_fillb(const int* __restrict__ src, const int* __restrict__ dst,
                        const float* __restrict__ ew, int* __restrict__ deg,
                        int2* __restrict__ bkt) {
  int e = (blockIdx.x * blockDim.x + threadIdx.x) * 4;
  if (e < NE) {  // NE % 4 == 0 -> e..e+3 valid
    int4 d = *reinterpret_cast<const int4*>(&dst[e]);
    int4 s = *reinterpret_cast<const int4*>(&src[e]);
    float4 w = *reinterpret_cast<const float4*>(&ew[e]);
    int p;
    p = atomicAdd(&deg[d.x], 1);
    if (p < CAP) bkt[(size_t)d.x * CAP + p] = make_int2(s.x, __float_as_int(w.x));
    p = atomicAdd(&deg[d.y], 1);
    if (p < CAP) bkt[(size_t)d.y * CAP + p] = make_int2(s.y, __float_as_int(w.y));
    p = atomicAdd(&deg[d.z], 1);
    if (p < CAP) bkt[(size_t)d.z * CAP + p] = make_int2(s.z, __float_as_int(w.z));
    p = atomicAdd(&deg[d.w], 1);
    if (p < CAP) bkt[(size_t)d.w * CAP + p] = make_int2(s.w, __float_as_int(w.w));
  }
}

// ---------------- Shared MLP body: X(LDS f16) @ Wa -> leaky -> @ Wb ----------
// A frag: row = wrow + (l&15) (+16), k = ks*32 + (l>>4)*8 + j (contiguous, LDS)
// B frag: fragment-linear whi/wlo, one 16B load each. acc2 = A*(Bhi+Blo).
__device__ __forceinline__ void mlp128(_Float16* __restrict__ Ah, int l, int wrow,
    const _Float16* __restrict__ Wahi, const _Float16* __restrict__ Walo,
    const float* __restrict__ ba,
    const _Float16* __restrict__ Wbhi, const _Float16* __restrict__ Wblo,
    f32x4 (&acc2)[2][8]) {
  const int arow0 = wrow + (l & 15);
  const int kgrp = (l >> 4) * 8;
  const int lcol = l & 15;

  f32x4 acc[2][8];
#pragma unroll
  for (int i = 0; i < 2; ++i)
#pragma unroll
    for (int j = 0; j < 8; ++j) acc[i][j] = f32x4{0.f, 0.f, 0.f, 0.f};

#pragma unroll
  for (int ks = 0; ks < 4; ++ks) {
    half8v a0 = *reinterpret_cast<const half8v*>(&Ah[arow0 * ASTRH + ks * 32 + kgrp]);
    half8v a1 = *reinterpret_cast<const half8v*>(&Ah[(arow0 + 16) * ASTRH + ks * 32 + kgrp]);
    const _Float16* wbh = &Wahi[(size_t)((ks * 8) * 64 + l) * 8];
    const _Float16* wbl = &Walo[(size_t)((ks * 8) * 64 + l) * 8];
#pragma unroll
    for (int fj = 0; fj < 8; ++fj) {
      half8v bh = *reinterpret_cast<const half8v*>(wbh + fj * 512);
      half8v bl = *reinterpret_cast<const half8v*>(wbl + fj * 512);
      acc[0][fj] = __builtin_amdgcn_mfma_f32_16x16x32_f16(a0, bh, acc[0][fj], 0, 0, 0);
      acc[0][fj] = __builtin_amdgcn_mfma_f32_16x16x32_f16(a0, bl, acc[0][fj], 0, 0, 0);
      acc[1][fj] = __builtin_amdgcn_mfma_f32_16x16x32_f16(a1, bh, acc[1][fj], 0, 0, 0);
      acc[1][fj] = __builtin_amdgcn_mfma_f32_16x16x32_f16(a1, bl, acc[1][fj], 0, 0, 0);
    }
  }

  // t = leaky(acc + ba) -> back into Ah (wave-local rows; same-wave LDS dep)
  {
    float bal[8];
#pragma unroll
    for (int fj = 0; fj < 8; ++fj) bal[fj] = ba[fj * 16 + lcol];
#pragma unroll
    for (int fi = 0; fi < 2; ++fi) {
      int rbase = wrow + fi * 16 + ((l >> 4) << 2);
#pragma unroll
      for (int fj = 0; fj < 8; ++fj) {
#pragma unroll
        for (int r = 0; r < 4; ++r) {
          float v = acc[fi][fj][r] + bal[fj];
          v = (v > 0.f) ? v : 0.01f * v;
          Ah[(rbase + r) * ASTRH + fj * 16 + lcol] = (_Float16)v;
        }
      }
    }
  }

#pragma unroll
  for (int i = 0; i < 2; ++i)
#pragma unroll
    for (int j = 0; j < 8; ++j) acc2[i][j] = f32x4{0.f, 0.f, 0.f, 0.f};

#pragma unroll
  for (int ks = 0; ks < 4; ++ks) {
    half8v a0 = *reinterpret_cast<const half8v*>(&Ah[arow0 * ASTRH + ks * 32 + kgrp]);
    half8v a1 = *reinterpret_cast<const half8v*>(&Ah[(arow0 + 16) * ASTRH + ks * 32 + kgrp]);
    const _Float16* wbh = &Wbhi[(size_t)((ks * 8) * 64 + l) * 8];
    const _Float16* wbl = &Wblo[(size_t)((ks * 8) * 64 + l) * 8];
#pragma unroll
    for (int fj = 0; fj < 8; ++fj) {
      half8v bh = *reinterpret_cast<const half8v*>(wbh + fj * 512);
      half8v bl = *reinterpret_cast<const half8v*>(wbl + fj * 512);
      acc2[0][fj] = __builtin_amdgcn_mfma_f32_16x16x32_f16(a0, bh, acc2[0][fj], 0, 0, 0);
      acc2[0][fj] = __builtin_amdgcn_mfma_f32_16x16x32_f16(a0, bl, acc2[0][fj], 0, 0, 0);
      acc2[1][fj] = __builtin_amdgcn_mfma_f32_16x16x32_f16(a1, bh, acc2[1][fj], 0, 0, 0);
      acc2[1][fj] = __builtin_amdgcn_mfma_f32_16x16x32_f16(a1, bl, acc2[1][fj], 0, 0, 0);
    }
  }
}

// ---------------- Fused layer1 + MLP1: x1 = relu(mlp(h1)), h1 built in LDS ----
// Layer-1 agg is rank-1 (2 scalars/edge); wave w computes its own A-rows
// [wrow, wrow+32) directly into LDS -> h1 never touches global memory.
__global__ __launch_bounds__(256, 2) void k_l1mlp(
    const float* __restrict__ nw, const int2* __restrict__ bkt,
    const int* __restrict__ deg,
    const float* __restrict__ Wn, const float* __restrict__ bn,
    const float* __restrict__ We, const float* __restrict__ be,
    const _Float16* __restrict__ Wahi, const _Float16* __restrict__ Walo,
    const float* __restrict__ ba,
    const _Float16* __restrict__ Wbhi, const _Float16* __restrict__ Wblo,
    const float* __restrict__ bb,
    _Float16* __restrict__ Y) {
  extern __shared__ char smem_raw[];
  _Float16* Ah = (_Float16*)smem_raw;
  const int tid = threadIdx.x;
  const int l = tid & 63;
  const int wrow = (tid >> 6) * 32;
  const int rowBase = blockIdx.x * 128;

  // ---- layer1 phase: rows [wrow, wrow+32) of this block's tile ----
  {
    int c = l * 2;
    float wn0 = Wn[c], wn1 = Wn[c + 1];
    float we0 = We[c], we1 = We[c + 1];
    float bn0 = bn[c], bn1 = bn[c + 1];
    float cb0 = bn0 + be[c], cb1 = bn1 + be[c + 1];
    for (int n = 0; n < 32; ++n) {
      int node = min(rowBase + wrow + n, NN - 1);
      float ai = nw[node];
      float acc0 = fmaf(ai, wn0, bn0);
      float acc1 = fmaf(ai, wn1, bn1);
      int kb = node * CAP;
      int k1 = kb + min(deg[node], CAP);
      int k = kb;
      for (; k + 4 <= k1; k += 4) {
        int2 p0 = bkt[k], p1 = bkt[k + 1], p2 = bkt[k + 2], p3 = bkt[k + 3];
        float a0 = nw[p0.x], a1 = nw[p1.x], a2 = nw[p2.x], a3 = nw[p3.x];
        float e0 = __int_as_float(p0.y), e1 = __int_as_float(p1.y);
        float e2 = __int_as_float(p2.y), e3 = __int_as_float(p3.y);
        acc0 += fmaxf(fmaf(a0, wn0, fmaf(e0, we0, cb0)), 0.f);
        acc1 += fmaxf(fmaf(a0, wn1, fmaf(e0, we1, cb1)), 0.f);
        acc0 += fmaxf(fmaf(a1, wn0, fmaf(e1, we0, cb0)), 0.f);
        acc1 += fmaxf(fmaf(a1, wn1, fmaf(e1, we1, cb1)), 0.f);
        acc0 += fmaxf(fmaf(a2, wn0, fmaf(e2, we0, cb0)), 0.f);
        acc1 += fmaxf(fmaf(a2, wn1, fmaf(e2, we1, cb1)), 0.f);
        acc0 += fmaxf(fmaf(a3, wn0, fmaf(e3, we0, cb0)), 0.f);
        acc1 += fmaxf(fmaf(a3, wn1, fmaf(e3, we1, cb1)), 0.f);
      }
      for (; k < k1; ++k) {
        int2 p = bkt[k];
        float a = nw[p.x];
        float b = __int_as_float(p.y);
        acc0 += fmaxf(fmaf(a, wn0, fmaf(b, we0, cb0)), 0.f);
        acc1 += fmaxf(fmaf(a, wn1, fmaf(b, we1, cb1)), 0.f);
      }
      half2v o; o[0] = (_Float16)acc0; o[1] = (_Float16)acc1;
      *reinterpret_cast<half2v*>(&Ah[(wrow + n) * ASTRH + c]) = o;
    }
  }
  __syncthreads();

  f32x4 acc2[2][8];
  mlp128(Ah, l, wrow, Wahi, Walo, ba, Wbhi, Wblo, acc2);

  const int lcol = l & 15;
  float bbl[8];
#pragma unroll
  for (int fj = 0; fj < 8; ++fj) bbl[fj] = bb[fj * 16 + lcol];
#pragma unroll
  for (int fi = 0; fi < 2; ++fi) {
    int rbase = wrow + fi * 16 + ((l >> 4) << 2);
#pragma unroll
    for (int fj = 0; fj < 8; ++fj) {
#pragma unroll
      for (int r = 0; r < 4; ++r) {
        int row = rowBase + rbase + r;
        if (row < NN)
          Y[(size_t)row * HID + fj * 16 + lcol] =
              (_Float16)fmaxf(acc2[fi][fj][r] + bbl[fj], 0.f);
      }
    }
  }
}

// ---------------- Fused layer2 + MLP2 + pool ----------------
// Layer-2 agg (x1 row gathers) builds this block's A-rows in LDS; h2 never
// touches global. x1 is fully written by the PREVIOUS kernel -> no race.
__global__ __launch_bounds__(256, 2) void k_l2mlp(
    const _Float16* __restrict__ x1, const int2* __restrict__ bkt,
    const int* __restrict__ deg,
    const float* __restrict__ We, const float* __restrict__ be,
    const _Float16* __restrict__ Wahi, const _Float16* __restrict__ Walo,
    const float* __restrict__ ba,
    const _Float16* __restrict__ Wbhi, const _Float16* __restrict__ Wblo,
    const float* __restrict__ bb,
    const int* __restrict__ batch, float* __restrict__ gsum) {
  extern __shared__ char smem_raw[];
  _Float16* Ah = (_Float16*)smem_raw;
  int* sB = (int*)(smem_raw + 128 * ASTRH * 2);
  const int tid = threadIdx.x;
  const int l = tid & 63;
  const int wrow = (tid >> 6) * 32;
  const int rowBase = blockIdx.x * 128;

  if (tid < 128) sB[tid] = batch[min(rowBase + tid, NN - 1)];

  // ---- layer2 phase: gather-aggregate rows [wrow, wrow+32) ----
  {
    int c = l * 2;
    float we0 = We[c], we1 = We[c + 1];
    float b0 = be[c], b1 = be[c + 1];
    for (int n = 0; n < 32; ++n) {
      int node = min(rowBase + wrow + n, NN - 1);
      half2v x = *reinterpret_cast<const half2v*>(&x1[(size_t)node * HID + c]);
      float acc0 = (float)x[0], acc1 = (float)x[1];
      int kb = node * CAP;
      int k1 = kb + min(deg[node], CAP);
      int k = kb;
      for (; k + 4 <= k1; k += 4) {
        int2 p0 = bkt[k], p1 = bkt[k + 1], p2 = bkt[k + 2], p3 = bkt[k + 3];
        half2v r0 = *reinterpret_cast<const half2v*>(&x1[(size_t)p0.x * HID + c]);
        half2v r1 = *reinterpret_cast<const half2v*>(&x1[(size_t)p1.x * HID + c]);
        half2v r2 = *reinterpret_cast<const half2v*>(&x1[(size_t)p2.x * HID + c]);
        half2v r3 = *reinterpret_cast<const half2v*>(&x1[(size_t)p3.x * HID + c]);
        float e0 = __int_as_float(p0.y), e1 = __int_as_float(p1.y);
        float e2 = __int_as_float(p2.y), e3 = __int_as_float(p3.y);
        acc0 += fmaxf((float)r0[0] + fmaf(e0, we0, b0), 0.f);
        acc1 += fmaxf((float)r0[1] + fmaf(e0, we1, b1), 0.f);
        acc0 += fmaxf((float)r1[0] + fmaf(e1, we0, b0), 0.f);
        acc1 += fmaxf((float)r1[1] + fmaf(e1, we1, b1), 0.f);
        acc0 += fmaxf((float)r2[0] + fmaf(e2, we0, b0), 0.f);
        acc1 += fmaxf((float)r2[1] + fmaf(e2, we1, b1), 0.f);
        acc0 += fmaxf((float)r3[0] + fmaf(e3, we0, b0), 0.f);
        acc1 += fmaxf((float)r3[1] + fmaf(e3, we1, b1), 0.f);
      }
      for (; k < k1; ++k) {
        int2 p = bkt[k];
        float b = __int_as_float(p.y);
        half2v xs = *reinterpret_cast<const half2v*>(&x1[(size_t)p.x * HID + c]);
        acc0 += fmaxf((float)xs[0] + fmaf(b, we0, b0), 0.f);
        acc1 += fmaxf((float)xs[1] + fmaf(b, we1, b1), 0.f);
      }
      half2v o; o[0] = (_Float16)acc0; o[1] = (_Float16)acc1;
      *reinterpret_cast<half2v*>(&Ah[(wrow + n) * ASTRH + c]) = o;
    }
  }
  __syncthreads();

  f32x4 acc2[2][8];
  mlp128(Ah, l, wrow, Wahi, Walo, ba, Wbhi, Wblo, acc2);

  const int lcol = l & 15;
  float bbl[8];
#pragma unroll
  for (int fj = 0; fj < 8; ++fj) bbl[fj] = bb[fj * 16 + lcol];

  __syncthreads();  // all waves done with Ah; reuse as f16 sPh[128][132]
  _Float16* sPh = (_Float16*)smem_raw;
#pragma unroll
  for (int fi = 0; fi < 2; ++fi) {
    int rbase = wrow + fi * 16 + ((l >> 4) << 2);
#pragma unroll
    for (int fj = 0; fj < 8; ++fj) {
#pragma unroll
      for (int r = 0; r < 4; ++r) {
        bool ok = (rowBase + rbase + r) < NN;
        float z = fmaxf(acc2[fi][fj][r] + bbl[fj], 0.f);
        sPh[(rbase + r) * 132 + fj * 16 + lcol] = (_Float16)(ok ? z : 0.f);
      }
    }
  }
  __syncthreads();
  if (tid < HID) {  // batch sorted: run-length reduce, few atomics/block
    int cur = sB[0];
    float run = 0.f;
    for (int r = 0; r < 128; ++r) {
      int g = sB[r];
      if (g != cur) {
        atomicAdd(&gsum[cur * HID + tid], run);
        run = 0.f; cur = g;
      }
      run += (float)sPh[r * 132 + tid];
    }
    atomicAdd(&gsum[cur * HID + tid], run);
  }
}

// ---------------- Final: pooled MLP -> sigmoid ----------------
__global__ void k_final(const float* __restrict__ gsum, const int* __restrict__ pos,
                        const float* __restrict__ Wm1, const float* __restrict__ bm1,
                        const float* __restrict__ Wm2, const float* __restrict__ bm2,
                        float* __restrict__ out) {
  __shared__ float sp[HID];
  __shared__ float red[HID];
  int g = blockIdx.x;
  int k = threadIdx.x;  // 128 threads
  float c = fmaxf((float)(pos[g + 1] - pos[g]), 1.f);
  sp[k] = gsum[g * HID + k] / c;
  __syncthreads();
  float dot = 0.f;
  for (int j = 0; j < HID; ++j) dot = fmaf(sp[j], Wm1[j * HID + k], dot);
  float z = dot + bm1[k];
  z = (z > 0.f) ? z : 0.01f * z;
  red[k] = z * Wm2[k];
  __syncthreads();
  for (int s = 64; s > 0; s >>= 1) {
    if (k < s) red[k] += red[k + s];
    __syncthreads();
  }
  if (k == 0) out[g] = 1.f / (1.f + expf(-(red[0] + bm2[0])));
}

extern "C" void kernel_launch(void* const* d_in, const int* in_sizes, int n_in,
                              void* d_out, int out_size, void* d_ws, size_t ws_size,
                              hipStream_t stream) {
  const float* nw = (const float*)d_in[0];
  const float* ew = (const float*)d_in[1];
  const int* ei = (const int*)d_in[2];
  const int* src = ei;
  const int* dst = ei + NE;
  const int* batch = (const int*)d_in[3];
  const float* Wn = (const float*)d_in[4];
  const float* bn = (const float*)d_in[5];
  const float* We = (const float*)d_in[6];
  const float* be = (const float*)d_in[7];
  const float* W1a = (const float*)d_in[8];
  const float* b1a = (const float*)d_in[9];
  const float* W1b = (const float*)d_in[10];
  const float* b1b = (const float*)d_in[11];
  const float* W2a = (const float*)d_in[12];
  const float* b2a = (const float*)d_in[13];
  const float* W2b = (const float*)d_in[14];
  const float* b2b = (const float*)d_in[15];
  const float* Wm1 = (const float*)d_in[16];
  const float* bm1 = (const float*)d_in[17];
  const float* Wm2 = (const float*)d_in[18];
  const float* bm2 = (const float*)d_in[19];
  float* out = (float*)d_out;

  char* ws = (char*)d_ws;
  size_t o = 0;
  auto alloc = [&](size_t b) {
    size_t p = o;
    o += (b + 255) & ~(size_t)255;
    return p;
  };
  size_t deg_o = alloc(NN * 4);
  size_t gsum_o = alloc((size_t)NG * HID * 4);
  size_t pos_o = alloc((NG + 1) * 4);
  size_t bkt_o = alloc((size_t)NN * CAP * 8);  // 19.2MB bucketed CSR
  size_t x1_o = alloc((size_t)NN * HID * 2);   // f16 x1 (only surviving intermediate)
  size_t whi_o = alloc((size_t)4 * 16384 * 2); // f16 hi, 4 matrices frag-linear
  size_t wlo_o = alloc((size_t)4 * 16384 * 2); // f16 lo

  int* deg = (int*)(ws + deg_o);
  float* gsum = (float*)(ws + gsum_o);
  int* pos = (int*)(ws + pos_o);
  int2* bkt = (int2*)(ws + bkt_o);
  _Float16* x1h = (_Float16*)(ws + x1_o);
  _Float16* whi = (_Float16*)(ws + whi_o);
  _Float16* wlo = (_Float16*)(ws + wlo_o);

  // 5 dispatches total (was 7)
  k_prep<<<277, 256, 0, stream>>>(batch, deg, gsum, pos, W1a, W1b, W2a, W2b, whi, wlo);
  k_fillb<<<(NE / 4 + 255) / 256, 256, 0, stream>>>(src, dst, ew, deg, bkt);

  size_t smem = (size_t)128 * ASTRH * 2 + 512;  // 35,328 B
  const int mlpBlocks = (NN + 127) / 128;  // 391
  k_l1mlp<<<mlpBlocks, 256, smem, stream>>>(nw, bkt, deg, Wn, bn, We, be,
                                            whi, wlo, b1a,
                                            whi + 16384, wlo + 16384, b1b, x1h);

  k_l2mlp<<<mlpBlocks, 256, smem, stream>>>(x1h, bkt, deg, We, be,
                                            whi + 2 * 16384, wlo + 2 * 16384, b2a,
                                            whi + 3 * 16384, wlo + 3 * 16384, b2b,
                                            batch, gsum);

  k_final<<<NG, HID, 0, stream>>>(gsum, pos, Wm1, bm1, Wm2, bm2, out);
}

// Round 11
// 172.619 us; speedup vs baseline: 1.4759x; 1.4759x over previous
//
#include <hip/hip_runtime.h>
#include <math.h>

#define NN 50000
#define NE 600000
#define HID 128
#define NG 64
#define CAP 48    // bucket capacity: Poisson(12) max-degree ~28; P(overflow)<1e-15
#define ASTRH 136 // LDS A-tile row stride in halves (272B): frag reads <=2-way

using half8v = __attribute__((ext_vector_type(8))) _Float16;
using half2v = __attribute__((ext_vector_type(2))) _Float16;
using f32x4  = __attribute__((ext_vector_type(4))) float;

// ---------------- Fused prep: pos boundaries | zero deg/gsum | weight split ----
__global__ void k_prep(const int* __restrict__ batch, int* __restrict__ deg,
                       float* __restrict__ gsum, int* __restrict__ pos,
                       const float* __restrict__ W1a, const float* __restrict__ W1b,
                       const float* __restrict__ W2a, const float* __restrict__ W2b,
                       _Float16* __restrict__ whi, _Float16* __restrict__ wlo) {
  int b = blockIdx.x, t = threadIdx.x;
  if (b < 196) {
    int i = b * 256 + t;
    if (i < NN) {
      int bb = batch[i];
      if (i == 0) {
        for (int g = 0; g <= bb; ++g) pos[g] = 0;
      } else {
        int bp = batch[i - 1];
        for (int g = bp + 1; g <= bb; ++g) pos[g] = i;
      }
      if (i == NN - 1) {
        for (int g = bb + 1; g <= NG; ++g) pos[g] = NN;
      }
    }
  } else if (b < 245) {
    int i = (b - 196) * 256 + t;
    if (i < 12500) reinterpret_cast<int4*>(deg)[i] = make_int4(0, 0, 0, 0);
    if (i < 2048) reinterpret_cast<float4*>(gsum)[i] = make_float4(0.f, 0.f, 0.f, 0.f);
  } else {
    int tid = (b - 245) * 256 + t;  // 0..8191
    int m = tid >> 11;
    const float* W = (m == 0) ? W1a : (m == 1) ? W1b : (m == 2) ? W2a : W2b;
    int rem = tid & 2047;
    int kt = rem >> 9;
    int fj = (rem >> 6) & 7;
    int l = rem & 63;
    int col = fj * 16 + (l & 15);
    int kbase = kt * 32 + (l >> 4) * 8;
    size_t obase = (size_t)m * 16384 + (size_t)(((kt * 8 + fj) * 64 + l)) * 8;
#pragma unroll
    for (int j = 0; j < 8; ++j) {
      float x = W[(size_t)(kbase + j) * HID + col];
      _Float16 h = (_Float16)x;
      whi[obase + j] = h;
      wlo[obase + j] = (_Float16)(x - (float)h);
    }
  }
}

// ---------------- One-pass bucketed CSR, 4 edges/thread ----------------
__global__ void k_fillb(const int* __restrict__ src, const int* __restrict__ dst,
                        const float* __restrict__ ew, int* __restrict__ deg,
                        int2* __restrict__ bkt) {
  int e = (blockIdx.x * blockDim.x + threadIdx.x) * 4;
  if (e < NE) {  // NE % 4 == 0 -> e..e+3 valid
    int4 d = *reinterpret_cast<const int4*>(&dst[e]);
    int4 s = *reinterpret_cast<const int4*>(&src[e]);
    float4 w = *reinterpret_cast<const float4*>(&ew[e]);
    int p;
    p = atomicAdd(&deg[d.x], 1);
    if (p < CAP) bkt[(size_t)d.x * CAP + p] = make_int2(s.x, __float_as_int(w.x));
    p = atomicAdd(&deg[d.y], 1);
    if (p < CAP) bkt[(size_t)d.y * CAP + p] = make_int2(s.y, __float_as_int(w.y));
    p = atomicAdd(&deg[d.z], 1);
    if (p < CAP) bkt[(size_t)d.z * CAP + p] = make_int2(s.z, __float_as_int(w.z));
    p = atomicAdd(&deg[d.w], 1);
    if (p < CAP) bkt[(size_t)d.w * CAP + p] = make_int2(s.w, __float_as_int(w.w));
  }
}

// ---------------- Layer 1 aggregation (rank-1: scalars only), f16 out ----------
__global__ void k_layer1(const float* __restrict__ nw, const int2* __restrict__ bkt,
                         const int* __restrict__ deg,
                         const float* __restrict__ Wn, const float* __restrict__ bn,
                         const float* __restrict__ We, const float* __restrict__ be,
                         _Float16* __restrict__ h) {
  int wave = threadIdx.x >> 6;
  int lane = threadIdx.x & 63;
  int node = blockIdx.x * 4 + wave;
  if (node >= NN) return;
  int c = lane * 2;
  float wn0 = Wn[c], wn1 = Wn[c + 1];
  float we0 = We[c], we1 = We[c + 1];
  float bn0 = bn[c], bn1 = bn[c + 1];
  float cb0 = bn0 + be[c], cb1 = bn1 + be[c + 1];
  float ai = nw[node];
  float acc0 = fmaf(ai, wn0, bn0);
  float acc1 = fmaf(ai, wn1, bn1);
  int k0 = node * CAP;
  int k1 = k0 + min(deg[node], CAP);
  int k = k0;
  for (; k + 4 <= k1; k += 4) {
    int2 p0 = bkt[k], p1 = bkt[k + 1], p2 = bkt[k + 2], p3 = bkt[k + 3];
    float a0 = nw[p0.x], a1 = nw[p1.x], a2 = nw[p2.x], a3 = nw[p3.x];
    float e0 = __int_as_float(p0.y), e1 = __int_as_float(p1.y);
    float e2 = __int_as_float(p2.y), e3 = __int_as_float(p3.y);
    acc0 += fmaxf(fmaf(a0, wn0, fmaf(e0, we0, cb0)), 0.f);
    acc1 += fmaxf(fmaf(a0, wn1, fmaf(e0, we1, cb1)), 0.f);
    acc0 += fmaxf(fmaf(a1, wn0, fmaf(e1, we0, cb0)), 0.f);
    acc1 += fmaxf(fmaf(a1, wn1, fmaf(e1, we1, cb1)), 0.f);
    acc0 += fmaxf(fmaf(a2, wn0, fmaf(e2, we0, cb0)), 0.f);
    acc1 += fmaxf(fmaf(a2, wn1, fmaf(e2, we1, cb1)), 0.f);
    acc0 += fmaxf(fmaf(a3, wn0, fmaf(e3, we0, cb0)), 0.f);
    acc1 += fmaxf(fmaf(a3, wn1, fmaf(e3, we1, cb1)), 0.f);
  }
  for (; k < k1; ++k) {
    int2 p = bkt[k];
    float a = nw[p.x];
    float b = __int_as_float(p.y);
    acc0 += fmaxf(fmaf(a, wn0, fmaf(b, we0, cb0)), 0.f);
    acc1 += fmaxf(fmaf(a, wn1, fmaf(b, we1, cb1)), 0.f);
  }
  half2v o; o[0] = (_Float16)acc0; o[1] = (_Float16)acc1;
  *reinterpret_cast<half2v*>(&h[(size_t)node * HID + c]) = o;
}

// ---------------- Layer 2 aggregation: f16 gathers, 4 in flight ----------------
__global__ void k_layer2(const _Float16* __restrict__ x1, const int2* __restrict__ bkt,
                         const int* __restrict__ deg,
                         const float* __restrict__ We, const float* __restrict__ be,
                         _Float16* __restrict__ h) {
  int wave = threadIdx.x >> 6;
  int lane = threadIdx.x & 63;
  int node = blockIdx.x * 4 + wave;
  if (node >= NN) return;
  int c = lane * 2;
  float we0 = We[c], we1 = We[c + 1];
  float b0 = be[c], b1 = be[c + 1];
  half2v x = *reinterpret_cast<const half2v*>(&x1[(size_t)node * HID + c]);
  float acc0 = (float)x[0], acc1 = (float)x[1];
  int k0 = node * CAP;
  int k1 = k0 + min(deg[node], CAP);
  int k = k0;
  for (; k + 4 <= k1; k += 4) {
    int2 p0 = bkt[k], p1 = bkt[k + 1], p2 = bkt[k + 2], p3 = bkt[k + 3];
    half2v r0 = *reinterpret_cast<const half2v*>(&x1[(size_t)p0.x * HID + c]);
    half2v r1 = *reinterpret_cast<const half2v*>(&x1[(size_t)p1.x * HID + c]);
    half2v r2 = *reinterpret_cast<const half2v*>(&x1[(size_t)p2.x * HID + c]);
    half2v r3 = *reinterpret_cast<const half2v*>(&x1[(size_t)p3.x * HID + c]);
    float e0 = __int_as_float(p0.y), e1 = __int_as_float(p1.y);
    float e2 = __int_as_float(p2.y), e3 = __int_as_float(p3.y);
    acc0 += fmaxf((float)r0[0] + fmaf(e0, we0, b0), 0.f);
    acc1 += fmaxf((float)r0[1] + fmaf(e0, we1, b1), 0.f);
    acc0 += fmaxf((float)r1[0] + fmaf(e1, we0, b0), 0.f);
    acc1 += fmaxf((float)r1[1] + fmaf(e1, we1, b1), 0.f);
    acc0 += fmaxf((float)r2[0] + fmaf(e2, we0, b0), 0.f);
    acc1 += fmaxf((float)r2[1] + fmaf(e2, we1, b1), 0.f);
    acc0 += fmaxf((float)r3[0] + fmaf(e3, we0, b0), 0.f);
    acc1 += fmaxf((float)r3[1] + fmaf(e3, we1, b1), 0.f);
  }
  for (; k < k1; ++k) {
    int2 p = bkt[k];
    float b = __int_as_float(p.y);
    half2v xs = *reinterpret_cast<const half2v*>(&x1[(size_t)p.x * HID + c]);
    acc0 += fmaxf((float)xs[0] + fmaf(b, we0, b0), 0.f);
    acc1 += fmaxf((float)xs[1] + fmaf(b, we1, b1), 0.f);
  }
  half2v o; o[0] = (_Float16)acc0; o[1] = (_Float16)acc1;
  *reinterpret_cast<half2v*>(&h[(size_t)node * HID + c]) = o;
}

// ---------------- MFMA MLP pair: Y = relu(leaky(X@Wa+ba)@Wb+bb) ----------------
// X is f16 (exact A operand). B split hi/lo: D = A*Bhi + A*Blo.
// Block = 128x128, 4 waves, wave owns rows [w*32, w*32+32). LDS: Ah[128][ASTRH]
// f16 (~35KB) -> 4 blocks/CU at __launch_bounds__(256,4) (VGPR cap 128, obs ~64-84).
template <int POOL>
__global__ __launch_bounds__(256, 4) void k_mlp(
    const _Float16* __restrict__ X,
    const _Float16* __restrict__ Wahi, const _Float16* __restrict__ Walo,
    const float* __restrict__ ba,
    const _Float16* __restrict__ Wbhi, const _Float16* __restrict__ Wblo,
    const float* __restrict__ bb,
    _Float16* __restrict__ Y,
    const int* __restrict__ batch, float* __restrict__ gsum) {
  extern __shared__ char smem_raw[];
  _Float16* Ah = (_Float16*)smem_raw;
  int* sB = (int*)(smem_raw + 128 * ASTRH * 2);
  const int tid = threadIdx.x;
  const int l = tid & 63;
  const int wrow = (tid >> 6) * 32;
  const int rowBase = blockIdx.x * 128;

  if (POOL && tid < 128) sB[tid] = batch[min(rowBase + tid, NN - 1)];

  // ---- stage X(f16) -> Ah (pure copy; 16 lanes cover one 256B row) ----
  {
    int rr = tid >> 4;         // 0..15
    int c0 = (tid & 15) * 8;   // 0..120
#pragma unroll
    for (int p = 0; p < 8; ++p) {
      int r = p * 16 + rr;
      int srcRow = min(rowBase + r, NN - 1);
      half8v v = *reinterpret_cast<const half8v*>(&X[(size_t)srcRow * HID + c0]);
      *reinterpret_cast<half8v*>(&Ah[r * ASTRH + c0]) = v;
    }
  }
  __syncthreads();

  const int arow0 = wrow + (l & 15);
  const int kgrp = (l >> 4) * 8;
  const int lcol = l & 15;

  // ---- GEMM1: acc = X @ Wa ----
  f32x4 acc[2][8];
#pragma unroll
  for (int i = 0; i < 2; ++i)
#pragma unroll
    for (int j = 0; j < 8; ++j) acc[i][j] = f32x4{0.f, 0.f, 0.f, 0.f};

#pragma unroll
  for (int ks = 0; ks < 4; ++ks) {
    half8v a0 = *reinterpret_cast<const half8v*>(&Ah[arow0 * ASTRH + ks * 32 + kgrp]);
    half8v a1 = *reinterpret_cast<const half8v*>(&Ah[(arow0 + 16) * ASTRH + ks * 32 + kgrp]);
    const _Float16* wbh = &Wahi[(size_t)((ks * 8) * 64 + l) * 8];
    const _Float16* wbl = &Walo[(size_t)((ks * 8) * 64 + l) * 8];
#pragma unroll
    for (int fj = 0; fj < 8; ++fj) {
      half8v bh = *reinterpret_cast<const half8v*>(wbh + fj * 512);
      half8v bl = *reinterpret_cast<const half8v*>(wbl + fj * 512);
      acc[0][fj] = __builtin_amdgcn_mfma_f32_16x16x32_f16(a0, bh, acc[0][fj], 0, 0, 0);
      acc[0][fj] = __builtin_amdgcn_mfma_f32_16x16x32_f16(a0, bl, acc[0][fj], 0, 0, 0);
      acc[1][fj] = __builtin_amdgcn_mfma_f32_16x16x32_f16(a1, bh, acc[1][fj], 0, 0, 0);
      acc[1][fj] = __builtin_amdgcn_mfma_f32_16x16x32_f16(a1, bl, acc[1][fj], 0, 0, 0);
    }
  }

  // ---- t = leaky(acc + ba) -> back into Ah (wave-local rows; no barrier) ----
  {
    float bal[8];
#pragma unroll
    for (int fj = 0; fj < 8; ++fj) bal[fj] = ba[fj * 16 + lcol];
#pragma unroll
    for (int fi = 0; fi < 2; ++fi) {
      int rbase = wrow + fi * 16 + ((l >> 4) << 2);
#pragma unroll
      for (int fj = 0; fj < 8; ++fj) {
#pragma unroll
        for (int r = 0; r < 4; ++r) {
          float v = acc[fi][fj][r] + bal[fj];
          v = (v > 0.f) ? v : 0.01f * v;
          Ah[(rbase + r) * ASTRH + fj * 16 + lcol] = (_Float16)v;
        }
      }
    }
  }

  // ---- GEMM2: acc2 = t @ Wb (t is wave-local in Ah) ----
  f32x4 acc2[2][8];
#pragma unroll
  for (int i = 0; i < 2; ++i)
#pragma unroll
    for (int j = 0; j < 8; ++j) acc2[i][j] = f32x4{0.f, 0.f, 0.f, 0.f};

#pragma unroll
  for (int ks = 0; ks < 4; ++ks) {
    half8v a0 = *reinterpret_cast<const half8v*>(&Ah[arow0 * ASTRH + ks * 32 + kgrp]);
    half8v a1 = *reinterpret_cast<const half8v*>(&Ah[(arow0 + 16) * ASTRH + ks * 32 + kgrp]);
    const _Float16* wbh = &Wbhi[(size_t)((ks * 8) * 64 + l) * 8];
    const _Float16* wbl = &Wblo[(size_t)((ks * 8) * 64 + l) * 8];
#pragma unroll
    for (int fj = 0; fj < 8; ++fj) {
      half8v bh = *reinterpret_cast<const half8v*>(wbh + fj * 512);
      half8v bl = *reinterpret_cast<const half8v*>(wbl + fj * 512);
      acc2[0][fj] = __builtin_amdgcn_mfma_f32_16x16x32_f16(a0, bh, acc2[0][fj], 0, 0, 0);
      acc2[0][fj] = __builtin_amdgcn_mfma_f32_16x16x32_f16(a0, bl, acc2[0][fj], 0, 0, 0);
      acc2[1][fj] = __builtin_amdgcn_mfma_f32_16x16x32_f16(a1, bh, acc2[1][fj], 0, 0, 0);
      acc2[1][fj] = __builtin_amdgcn_mfma_f32_16x16x32_f16(a1, bl, acc2[1][fj], 0, 0, 0);
    }
  }

  // ---- epilogue: relu(acc2 + bb) ----
  float bbl[8];
#pragma unroll
  for (int fj = 0; fj < 8; ++fj) bbl[fj] = bb[fj * 16 + lcol];

  if (!POOL) {
#pragma unroll
    for (int fi = 0; fi < 2; ++fi) {
      int rbase = wrow + fi * 16 + ((l >> 4) << 2);
#pragma unroll
      for (int fj = 0; fj < 8; ++fj) {
#pragma unroll
        for (int r = 0; r < 4; ++r) {
          int row = rowBase + rbase + r;
          if (row < NN)
            Y[(size_t)row * HID + fj * 16 + lcol] =
                (_Float16)fmaxf(acc2[fi][fj][r] + bbl[fj], 0.f);
        }
      }
    }
  } else {
    __syncthreads();  // other waves done with Ah; reuse as f16 sPh[128][132]
    _Float16* sPh = (_Float16*)smem_raw;
#pragma unroll
    for (int fi = 0; fi < 2; ++fi) {
      int rbase = wrow + fi * 16 + ((l >> 4) << 2);
#pragma unroll
      for (int fj = 0; fj < 8; ++fj) {
#pragma unroll
        for (int r = 0; r < 4; ++r) {
          bool ok = (rowBase + rbase + r) < NN;
          float z = fmaxf(acc2[fi][fj][r] + bbl[fj], 0.f);
          sPh[(rbase + r) * 132 + fj * 16 + lcol] = (_Float16)(ok ? z : 0.f);
        }
      }
    }
    __syncthreads();
    if (tid < HID) {  // batch sorted: run-length reduce, few atomics/block
      int cur = sB[0];
      float run = 0.f;
      for (int r = 0; r < 128; ++r) {
        int g = sB[r];
        if (g != cur) {
          atomicAdd(&gsum[cur * HID + tid], run);
          run = 0.f; cur = g;
        }
        run += (float)sPh[r * 132 + tid];
      }
      atomicAdd(&gsum[cur * HID + tid], run);
    }
  }
}

// ---------------- Final: pooled MLP -> sigmoid ----------------
__global__ void k_final(const float* __restrict__ gsum, const int* __restrict__ pos,
                        const float* __restrict__ Wm1, const float* __restrict__ bm1,
                        const float* __restrict__ Wm2, const float* __restrict__ bm2,
                        float* __restrict__ out) {
  __shared__ float sp[HID];
  __shared__ float red[HID];
  int g = blockIdx.x;
  int k = threadIdx.x;  // 128 threads
  float c = fmaxf((float)(pos[g + 1] - pos[g]), 1.f);
  sp[k] = gsum[g * HID + k] / c;
  __syncthreads();
  float dot = 0.f;
  for (int j = 0; j < HID; ++j) dot = fmaf(sp[j], Wm1[j * HID + k], dot);
  float z = dot + bm1[k];
  z = (z > 0.f) ? z : 0.01f * z;
  red[k] = z * Wm2[k];
  __syncthreads();
  for (int s = 64; s > 0; s >>= 1) {
    if (k < s) red[k] += red[k + s];
    __syncthreads();
  }
  if (k == 0) out[g] = 1.f / (1.f + expf(-(red[0] + bm2[0])));
}

extern "C" void kernel_launch(void* const* d_in, const int* in_sizes, int n_in,
                              void* d_out, int out_size, void* d_ws, size_t ws_size,
                              hipStream_t stream) {
  const float* nw = (const float*)d_in[0];
  const float* ew = (const float*)d_in[1];
  const int* ei = (const int*)d_in[2];
  const int* src = ei;
  const int* dst = ei + NE;
  const int* batch = (const int*)d_in[3];
  const float* Wn = (const float*)d_in[4];
  const float* bn = (const float*)d_in[5];
  const float* We = (const float*)d_in[6];
  const float* be = (const float*)d_in[7];
  const float* W1a = (const float*)d_in[8];
  const float* b1a = (const float*)d_in[9];
  const float* W1b = (const float*)d_in[10];
  const float* b1b = (const float*)d_in[11];
  const float* W2a = (const float*)d_in[12];
  const float* b2a = (const float*)d_in[13];
  const float* W2b = (const float*)d_in[14];
  const float* b2b = (const float*)d_in[15];
  const float* Wm1 = (const float*)d_in[16];
  const float* bm1 = (const float*)d_in[17];
  const float* Wm2 = (const float*)d_in[18];
  const float* bm2 = (const float*)d_in[19];
  float* out = (float*)d_out;

  char* ws = (char*)d_ws;
  size_t o = 0;
  auto alloc = [&](size_t b) {
    size_t p = o;
    o += (b + 255) & ~(size_t)255;
    return p;
  };
  size_t deg_o = alloc(NN * 4);
  size_t gsum_o = alloc((size_t)NG * HID * 4);
  size_t pos_o = alloc((NG + 1) * 4);
  size_t bkt_o = alloc((size_t)NN * CAP * 8);  // 19.2MB bucketed CSR
  size_t h1_o = alloc((size_t)NN * HID * 2);   // f16 node features (layer1 out)
  size_t x1_o = alloc((size_t)NN * HID * 2);   // f16 x1 (mlp0 out)
  size_t h2_o = alloc((size_t)NN * HID * 2);   // f16 (layer2 out)
  size_t whi_o = alloc((size_t)4 * 16384 * 2); // f16 hi, 4 matrices frag-linear
  size_t wlo_o = alloc((size_t)4 * 16384 * 2); // f16 lo

  int* deg = (int*)(ws + deg_o);
  float* gsum = (float*)(ws + gsum_o);
  int* pos = (int*)(ws + pos_o);
  int2* bkt = (int2*)(ws + bkt_o);
  _Float16* h1 = (_Float16*)(ws + h1_o);
  _Float16* x1h = (_Float16*)(ws + x1_o);
  _Float16* h2 = (_Float16*)(ws + h2_o);
  _Float16* whi = (_Float16*)(ws + whi_o);
  _Float16* wlo = (_Float16*)(ws + wlo_o);

  // 7 dispatches (R9 structure; fusion of gather into GEMM grid regressed in R10)
  k_prep<<<277, 256, 0, stream>>>(batch, deg, gsum, pos, W1a, W1b, W2a, W2b, whi, wlo);
  k_fillb<<<(NE / 4 + 255) / 256, 256, 0, stream>>>(src, dst, ew, deg, bkt);

  k_layer1<<<NN / 4, 256, 0, stream>>>(nw, bkt, deg, Wn, bn, We, be, h1);

  size_t smem = (size_t)128 * ASTRH * 2 + 512;  // 35,328 B -> 4 blocks/CU
  const int mlpBlocks = (NN + 127) / 128;  // 391
  k_mlp<0><<<mlpBlocks, 256, smem, stream>>>(h1, whi, wlo, b1a,
                                             whi + 16384, wlo + 16384, b1b,
                                             x1h, nullptr, nullptr);

  k_layer2<<<NN / 4, 256, 0, stream>>>(x1h, bkt, deg, We, be, h2);

  k_mlp<1><<<mlpBlocks, 256, smem, stream>>>(h2, whi + 2 * 16384, wlo + 2 * 16384, b2a,
                                             whi + 3 * 16384, wlo + 3 * 16384, b2b,
                                             nullptr, batch, gsum);

  k_final<<<NG, HID, 0, stream>>>(gsum, pos, Wm1, bm1, Wm2, bm2, out);
}

// Round 12
// 169.946 us; speedup vs baseline: 1.4991x; 1.0157x over previous
//
#include <hip/hip_runtime.h>
#include <math.h>

#define NN 50000
#define NE 600000
#define HID 128
#define NG 64
#define CAP 48    // bucket capacity: Poisson(12) max-degree ~28; P(overflow)<1e-15
#define ASTRH 136 // LDS A-tile row stride in halves (272B): frag reads <=2-way

using half8v = __attribute__((ext_vector_type(8))) _Float16;
using half2v = __attribute__((ext_vector_type(2))) _Float16;
using f32x4  = __attribute__((ext_vector_type(4))) float;

__device__ __forceinline__ float unpack_w(unsigned p) {
  return (float)__builtin_bit_cast(_Float16, (unsigned short)(p & 0xffffu));
}

// ---------------- Fused prep: pos boundaries | zero deg/gsum | weight split ----
__global__ void k_prep(const int* __restrict__ batch, int* __restrict__ deg,
                       float* __restrict__ gsum, int* __restrict__ pos,
                       const float* __restrict__ W1a, const float* __restrict__ W1b,
                       const float* __restrict__ W2a, const float* __restrict__ W2b,
                       _Float16* __restrict__ whi, _Float16* __restrict__ wlo) {
  int b = blockIdx.x, t = threadIdx.x;
  if (b < 196) {
    int i = b * 256 + t;
    if (i < NN) {
      int bb = batch[i];
      if (i == 0) {
        for (int g = 0; g <= bb; ++g) pos[g] = 0;
      } else {
        int bp = batch[i - 1];
        for (int g = bp + 1; g <= bb; ++g) pos[g] = i;
      }
      if (i == NN - 1) {
        for (int g = bb + 1; g <= NG; ++g) pos[g] = NN;
      }
    }
  } else if (b < 245) {
    int i = (b - 196) * 256 + t;
    if (i < 12500) reinterpret_cast<int4*>(deg)[i] = make_int4(0, 0, 0, 0);
    if (i < 2048) reinterpret_cast<float4*>(gsum)[i] = make_float4(0.f, 0.f, 0.f, 0.f);
  } else {
    int tid = (b - 245) * 256 + t;  // 0..8191
    int m = tid >> 11;
    const float* W = (m == 0) ? W1a : (m == 1) ? W1b : (m == 2) ? W2a : W2b;
    int rem = tid & 2047;
    int kt = rem >> 9;
    int fj = (rem >> 6) & 7;
    int l = rem & 63;
    int col = fj * 16 + (l & 15);
    int kbase = kt * 32 + (l >> 4) * 8;
    size_t obase = (size_t)m * 16384 + (size_t)(((kt * 8 + fj) * 64 + l)) * 8;
#pragma unroll
    for (int j = 0; j < 8; ++j) {
      float x = W[(size_t)(kbase + j) * HID + col];
      _Float16 h = (_Float16)x;
      whi[obase + j] = h;
      wlo[obase + j] = (_Float16)(x - (float)h);
    }
  }
}

// ---------------- One-pass bucketed CSR, 4B packed entries, 1 edge/thread ------
// entry = (src << 16) | f16bits(ew): src < 50000 < 2^16. Bucket row 192B;
// ~12 live entries = 48B -> ~1 dirty 64B sector/node (was ~5 with 8B entries).
__global__ void k_fillb(const int* __restrict__ src, const int* __restrict__ dst,
                        const float* __restrict__ ew, int* __restrict__ deg,
                        unsigned* __restrict__ bkt) {
  int e = blockIdx.x * blockDim.x + threadIdx.x;
  if (e < NE) {
    int d = dst[e];
    int p = atomicAdd(&deg[d], 1);
    if (p < CAP) {
      _Float16 w = (_Float16)ew[e];
      unsigned wb = (unsigned)__builtin_bit_cast(unsigned short, w);
      bkt[d * CAP + p] = ((unsigned)src[e] << 16) | wb;
    }
  }
}

// ---------------- Layer 1 aggregation (rank-1: scalars only), f16 out ----------
// CSR entries read 4-at-a-time via uint4 (bucket base 192B-aligned).
__global__ void k_layer1(const float* __restrict__ nw, const unsigned* __restrict__ bkt,
                         const int* __restrict__ deg,
                         const float* __restrict__ Wn, const float* __restrict__ bn,
                         const float* __restrict__ We, const float* __restrict__ be,
                         _Float16* __restrict__ h) {
  int wave = threadIdx.x >> 6;
  int lane = threadIdx.x & 63;
  int node = blockIdx.x * 4 + wave;
  if (node >= NN) return;
  int c = lane * 2;
  float wn0 = Wn[c], wn1 = Wn[c + 1];
  float we0 = We[c], we1 = We[c + 1];
  float bn0 = bn[c], bn1 = bn[c + 1];
  float cb0 = bn0 + be[c], cb1 = bn1 + be[c + 1];
  float ai = nw[node];
  float acc0 = fmaf(ai, wn0, bn0);
  float acc1 = fmaf(ai, wn1, bn1);
  int k0 = node * CAP;
  int cnt = min(deg[node], CAP);
  int k = 0;
  for (; k + 4 <= cnt; k += 4) {
    uint4 q = *reinterpret_cast<const uint4*>(&bkt[k0 + k]);
    float a0 = nw[q.x >> 16], a1 = nw[q.y >> 16];
    float a2 = nw[q.z >> 16], a3 = nw[q.w >> 16];
    float e0 = unpack_w(q.x), e1 = unpack_w(q.y);
    float e2 = unpack_w(q.z), e3 = unpack_w(q.w);
    acc0 += fmaxf(fmaf(a0, wn0, fmaf(e0, we0, cb0)), 0.f);
    acc1 += fmaxf(fmaf(a0, wn1, fmaf(e0, we1, cb1)), 0.f);
    acc0 += fmaxf(fmaf(a1, wn0, fmaf(e1, we0, cb0)), 0.f);
    acc1 += fmaxf(fmaf(a1, wn1, fmaf(e1, we1, cb1)), 0.f);
    acc0 += fmaxf(fmaf(a2, wn0, fmaf(e2, we0, cb0)), 0.f);
    acc1 += fmaxf(fmaf(a2, wn1, fmaf(e2, we1, cb1)), 0.f);
    acc0 += fmaxf(fmaf(a3, wn0, fmaf(e3, we0, cb0)), 0.f);
    acc1 += fmaxf(fmaf(a3, wn1, fmaf(e3, we1, cb1)), 0.f);
  }
  for (; k < cnt; ++k) {
    unsigned p = bkt[k0 + k];
    float a = nw[p >> 16];
    float b = unpack_w(p);
    acc0 += fmaxf(fmaf(a, wn0, fmaf(b, we0, cb0)), 0.f);
    acc1 += fmaxf(fmaf(a, wn1, fmaf(b, we1, cb1)), 0.f);
  }
  half2v o; o[0] = (_Float16)acc0; o[1] = (_Float16)acc1;
  *reinterpret_cast<half2v*>(&h[(size_t)node * HID + c]) = o;
}

// ---------------- Layer 2 aggregation: f16 gathers, 4 in flight ----------------
__global__ void k_layer2(const _Float16* __restrict__ x1, const unsigned* __restrict__ bkt,
                         const int* __restrict__ deg,
                         const float* __restrict__ We, const float* __restrict__ be,
                         _Float16* __restrict__ h) {
  int wave = threadIdx.x >> 6;
  int lane = threadIdx.x & 63;
  int node = blockIdx.x * 4 + wave;
  if (node >= NN) return;
  int c = lane * 2;
  float we0 = We[c], we1 = We[c + 1];
  float b0 = be[c], b1 = be[c + 1];
  half2v x = *reinterpret_cast<const half2v*>(&x1[(size_t)node * HID + c]);
  float acc0 = (float)x[0], acc1 = (float)x[1];
  int k0 = node * CAP;
  int cnt = min(deg[node], CAP);
  int k = 0;
  for (; k + 4 <= cnt; k += 4) {
    uint4 q = *reinterpret_cast<const uint4*>(&bkt[k0 + k]);
    half2v r0 = *reinterpret_cast<const half2v*>(&x1[(size_t)(q.x >> 16) * HID + c]);
    half2v r1 = *reinterpret_cast<const half2v*>(&x1[(size_t)(q.y >> 16) * HID + c]);
    half2v r2 = *reinterpret_cast<const half2v*>(&x1[(size_t)(q.z >> 16) * HID + c]);
    half2v r3 = *reinterpret_cast<const half2v*>(&x1[(size_t)(q.w >> 16) * HID + c]);
    float e0 = unpack_w(q.x), e1 = unpack_w(q.y);
    float e2 = unpack_w(q.z), e3 = unpack_w(q.w);
    acc0 += fmaxf((float)r0[0] + fmaf(e0, we0, b0), 0.f);
    acc1 += fmaxf((float)r0[1] + fmaf(e0, we1, b1), 0.f);
    acc0 += fmaxf((float)r1[0] + fmaf(e1, we0, b0), 0.f);
    acc1 += fmaxf((float)r1[1] + fmaf(e1, we1, b1), 0.f);
    acc0 += fmaxf((float)r2[0] + fmaf(e2, we0, b0), 0.f);
    acc1 += fmaxf((float)r2[1] + fmaf(e2, we1, b1), 0.f);
    acc0 += fmaxf((float)r3[0] + fmaf(e3, we0, b0), 0.f);
    acc1 += fmaxf((float)r3[1] + fmaf(e3, we1, b1), 0.f);
  }
  for (; k < cnt; ++k) {
    unsigned p = bkt[k0 + k];
    float b = unpack_w(p);
    half2v xs = *reinterpret_cast<const half2v*>(&x1[(size_t)(p >> 16) * HID + c]);
    acc0 += fmaxf((float)xs[0] + fmaf(b, we0, b0), 0.f);
    acc1 += fmaxf((float)xs[1] + fmaf(b, we1, b1), 0.f);
  }
  half2v o; o[0] = (_Float16)acc0; o[1] = (_Float16)acc1;
  *reinterpret_cast<half2v*>(&h[(size_t)node * HID + c]) = o;
}

// ---------------- MFMA MLP pair: Y = relu(leaky(X@Wa+ba)@Wb+bb) ----------------
// X is f16 (exact A operand). B split hi/lo: D = A*Bhi + A*Blo.
// Block = 128x128, 4 waves, wave owns rows [w*32, w*32+32). LDS: Ah[128][ASTRH]
// f16 (~35KB) -> 4 blocks/CU at __launch_bounds__(256,4).
template <int POOL>
__global__ __launch_bounds__(256, 4) void k_mlp(
    const _Float16* __restrict__ X,
    const _Float16* __restrict__ Wahi, const _Float16* __restrict__ Walo,
    const float* __restrict__ ba,
    const _Float16* __restrict__ Wbhi, const _Float16* __restrict__ Wblo,
    const float* __restrict__ bb,
    _Float16* __restrict__ Y,
    const int* __restrict__ batch, float* __restrict__ gsum) {
  extern __shared__ char smem_raw[];
  _Float16* Ah = (_Float16*)smem_raw;
  int* sB = (int*)(smem_raw + 128 * ASTRH * 2);
  const int tid = threadIdx.x;
  const int l = tid & 63;
  const int wrow = (tid >> 6) * 32;
  const int rowBase = blockIdx.x * 128;

  if (POOL && tid < 128) sB[tid] = batch[min(rowBase + tid, NN - 1)];

  // ---- stage X(f16) -> Ah (pure copy; 16 lanes cover one 256B row) ----
  {
    int rr = tid >> 4;         // 0..15
    int c0 = (tid & 15) * 8;   // 0..120
#pragma unroll
    for (int p = 0; p < 8; ++p) {
      int r = p * 16 + rr;
      int srcRow = min(rowBase + r, NN - 1);
      half8v v = *reinterpret_cast<const half8v*>(&X[(size_t)srcRow * HID + c0]);
      *reinterpret_cast<half8v*>(&Ah[r * ASTRH + c0]) = v;
    }
  }
  __syncthreads();

  const int arow0 = wrow + (l & 15);
  const int kgrp = (l >> 4) * 8;
  const int lcol = l & 15;

  // ---- GEMM1: acc = X @ Wa ----
  f32x4 acc[2][8];
#pragma unroll
  for (int i = 0; i < 2; ++i)
#pragma unroll
    for (int j = 0; j < 8; ++j) acc[i][j] = f32x4{0.f, 0.f, 0.f, 0.f};

#pragma unroll
  for (int ks = 0; ks < 4; ++ks) {
    half8v a0 = *reinterpret_cast<const half8v*>(&Ah[arow0 * ASTRH + ks * 32 + kgrp]);
    half8v a1 = *reinterpret_cast<const half8v*>(&Ah[(arow0 + 16) * ASTRH + ks * 32 + kgrp]);
    const _Float16* wbh = &Wahi[(size_t)((ks * 8) * 64 + l) * 8];
    const _Float16* wbl = &Walo[(size_t)((ks * 8) * 64 + l) * 8];
#pragma unroll
    for (int fj = 0; fj < 8; ++fj) {
      half8v bh = *reinterpret_cast<const half8v*>(wbh + fj * 512);
      half8v bl = *reinterpret_cast<const half8v*>(wbl + fj * 512);
      acc[0][fj] = __builtin_amdgcn_mfma_f32_16x16x32_f16(a0, bh, acc[0][fj], 0, 0, 0);
      acc[0][fj] = __builtin_amdgcn_mfma_f32_16x16x32_f16(a0, bl, acc[0][fj], 0, 0, 0);
      acc[1][fj] = __builtin_amdgcn_mfma_f32_16x16x32_f16(a1, bh, acc[1][fj], 0, 0, 0);
      acc[1][fj] = __builtin_amdgcn_mfma_f32_16x16x32_f16(a1, bl, acc[1][fj], 0, 0, 0);
    }
  }

  // ---- t = leaky(acc + ba) -> back into Ah (wave-local rows; no barrier) ----
  {
    float bal[8];
#pragma unroll
    for (int fj = 0; fj < 8; ++fj) bal[fj] = ba[fj * 16 + lcol];
#pragma unroll
    for (int fi = 0; fi < 2; ++fi) {
      int rbase = wrow + fi * 16 + ((l >> 4) << 2);
#pragma unroll
      for (int fj = 0; fj < 8; ++fj) {
#pragma unroll
        for (int r = 0; r < 4; ++r) {
          float v = acc[fi][fj][r] + bal[fj];
          v = (v > 0.f) ? v : 0.01f * v;
          Ah[(rbase + r) * ASTRH + fj * 16 + lcol] = (_Float16)v;
        }
      }
    }
  }

  // ---- GEMM2: acc2 = t @ Wb (t is wave-local in Ah) ----
  f32x4 acc2[2][8];
#pragma unroll
  for (int i = 0; i < 2; ++i)
#pragma unroll
    for (int j = 0; j < 8; ++j) acc2[i][j] = f32x4{0.f, 0.f, 0.f, 0.f};

#pragma unroll
  for (int ks = 0; ks < 4; ++ks) {
    half8v a0 = *reinterpret_cast<const half8v*>(&Ah[arow0 * ASTRH + ks * 32 + kgrp]);
    half8v a1 = *reinterpret_cast<const half8v*>(&Ah[(arow0 + 16) * ASTRH + ks * 32 + kgrp]);
    const _Float16* wbh = &Wbhi[(size_t)((ks * 8) * 64 + l) * 8];
    const _Float16* wbl = &Wblo[(size_t)((ks * 8) * 64 + l) * 8];
#pragma unroll
    for (int fj = 0; fj < 8; ++fj) {
      half8v bh = *reinterpret_cast<const half8v*>(wbh + fj * 512);
      half8v bl = *reinterpret_cast<const half8v*>(wbl + fj * 512);
      acc2[0][fj] = __builtin_amdgcn_mfma_f32_16x16x32_f16(a0, bh, acc2[0][fj], 0, 0, 0);
      acc2[0][fj] = __builtin_amdgcn_mfma_f32_16x16x32_f16(a0, bl, acc2[0][fj], 0, 0, 0);
      acc2[1][fj] = __builtin_amdgcn_mfma_f32_16x16x32_f16(a1, bh, acc2[1][fj], 0, 0, 0);
      acc2[1][fj] = __builtin_amdgcn_mfma_f32_16x16x32_f16(a1, bl, acc2[1][fj], 0, 0, 0);
    }
  }

  // ---- epilogue: relu(acc2 + bb) ----
  float bbl[8];
#pragma unroll
  for (int fj = 0; fj < 8; ++fj) bbl[fj] = bb[fj * 16 + lcol];

  if (!POOL) {
#pragma unroll
    for (int fi = 0; fi < 2; ++fi) {
      int rbase = wrow + fi * 16 + ((l >> 4) << 2);
#pragma unroll
      for (int fj = 0; fj < 8; ++fj) {
#pragma unroll
        for (int r = 0; r < 4; ++r) {
          int row = rowBase + rbase + r;
          if (row < NN)
            Y[(size_t)row * HID + fj * 16 + lcol] =
                (_Float16)fmaxf(acc2[fi][fj][r] + bbl[fj], 0.f);
        }
      }
    }
  } else {
    __syncthreads();  // other waves done with Ah; reuse as f16 sPh[128][132]
    _Float16* sPh = (_Float16*)smem_raw;
#pragma unroll
    for (int fi = 0; fi < 2; ++fi) {
      int rbase = wrow + fi * 16 + ((l >> 4) << 2);
#pragma unroll
      for (int fj = 0; fj < 8; ++fj) {
#pragma unroll
        for (int r = 0; r < 4; ++r) {
          bool ok = (rowBase + rbase + r) < NN;
          float z = fmaxf(acc2[fi][fj][r] + bbl[fj], 0.f);
          sPh[(rbase + r) * 132 + fj * 16 + lcol] = (_Float16)(ok ? z : 0.f);
        }
      }
    }
    __syncthreads();
    if (tid < HID) {  // batch sorted: run-length reduce, few atomics/block
      int cur = sB[0];
      float run = 0.f;
      for (int r = 0; r < 128; ++r) {
        int g = sB[r];
        if (g != cur) {
          atomicAdd(&gsum[cur * HID + tid], run);
          run = 0.f; cur = g;
        }
        run += (float)sPh[r * 132 + tid];
      }
      atomicAdd(&gsum[cur * HID + tid], run);
    }
  }
}

// ---------------- Final: pooled MLP -> sigmoid ----------------
__global__ void k_final(const float* __restrict__ gsum, const int* __restrict__ pos,
                        const float* __restrict__ Wm1, const float* __restrict__ bm1,
                        const float* __restrict__ Wm2, const float* __restrict__ bm2,
                        float* __restrict__ out) {
  __shared__ float sp[HID];
  __shared__ float red[HID];
  int g = blockIdx.x;
  int k = threadIdx.x;  // 128 threads
  float c = fmaxf((float)(pos[g + 1] - pos[g]), 1.f);
  sp[k] = gsum[g * HID + k] / c;
  __syncthreads();
  float dot = 0.f;
  for (int j = 0; j < HID; ++j) dot = fmaf(sp[j], Wm1[j * HID + k], dot);
  float z = dot + bm1[k];
  z = (z > 0.f) ? z : 0.01f * z;
  red[k] = z * Wm2[k];
  __syncthreads();
  for (int s = 64; s > 0; s >>= 1) {
    if (k < s) red[k] += red[k + s];
    __syncthreads();
  }
  if (k == 0) out[g] = 1.f / (1.f + expf(-(red[0] + bm2[0])));
}

extern "C" void kernel_launch(void* const* d_in, const int* in_sizes, int n_in,
                              void* d_out, int out_size, void* d_ws, size_t ws_size,
                              hipStream_t stream) {
  const float* nw = (const float*)d_in[0];
  const float* ew = (const float*)d_in[1];
  const int* ei = (const int*)d_in[2];
  const int* src = ei;
  const int* dst = ei + NE;
  const int* batch = (const int*)d_in[3];
  const float* Wn = (const float*)d_in[4];
  const float* bn = (const float*)d_in[5];
  const float* We = (const float*)d_in[6];
  const float* be = (const float*)d_in[7];
  const float* W1a = (const float*)d_in[8];
  const float* b1a = (const float*)d_in[9];
  const float* W1b = (const float*)d_in[10];
  const float* b1b = (const float*)d_in[11];
  const float* W2a = (const float*)d_in[12];
  const float* b2a = (const float*)d_in[13];
  const float* W2b = (const float*)d_in[14];
  const float* b2b = (const float*)d_in[15];
  const float* Wm1 = (const float*)d_in[16];
  const float* bm1 = (const float*)d_in[17];
  const float* Wm2 = (const float*)d_in[18];
  const float* bm2 = (const float*)d_in[19];
  float* out = (float*)d_out;

  char* ws = (char*)d_ws;
  size_t o = 0;
  auto alloc = [&](size_t b) {
    size_t p = o;
    o += (b + 255) & ~(size_t)255;
    return p;
  };
  size_t deg_o = alloc(NN * 4);
  size_t gsum_o = alloc((size_t)NG * HID * 4);
  size_t pos_o = alloc((NG + 1) * 4);
  size_t bkt_o = alloc((size_t)NN * CAP * 4);  // 9.6MB packed-u32 bucketed CSR
  size_t h1_o = alloc((size_t)NN * HID * 2);   // f16 node features (layer1 out)
  size_t x1_o = alloc((size_t)NN * HID * 2);   // f16 x1 (mlp0 out)
  size_t h2_o = alloc((size_t)NN * HID * 2);   // f16 (layer2 out)
  size_t whi_o = alloc((size_t)4 * 16384 * 2); // f16 hi, 4 matrices frag-linear
  size_t wlo_o = alloc((size_t)4 * 16384 * 2); // f16 lo

  int* deg = (int*)(ws + deg_o);
  float* gsum = (float*)(ws + gsum_o);
  int* pos = (int*)(ws + pos_o);
  unsigned* bkt = (unsigned*)(ws + bkt_o);
  _Float16* h1 = (_Float16*)(ws + h1_o);
  _Float16* x1h = (_Float16*)(ws + x1_o);
  _Float16* h2 = (_Float16*)(ws + h2_o);
  _Float16* whi = (_Float16*)(ws + whi_o);
  _Float16* wlo = (_Float16*)(ws + wlo_o);

  // 7 dispatches
  k_prep<<<277, 256, 0, stream>>>(batch, deg, gsum, pos, W1a, W1b, W2a, W2b, whi, wlo);
  k_fillb<<<(NE + 255) / 256, 256, 0, stream>>>(src, dst, ew, deg, bkt);

  k_layer1<<<NN / 4, 256, 0, stream>>>(nw, bkt, deg, Wn, bn, We, be, h1);

  size_t smem = (size_t)128 * ASTRH * 2 + 512;  // 35,328 B -> 4 blocks/CU
  const int mlpBlocks = (NN + 127) / 128;  // 391
  k_mlp<0><<<mlpBlocks, 256, smem, stream>>>(h1, whi, wlo, b1a,
                                             whi + 16384, wlo + 16384, b1b,
                                             x1h, nullptr, nullptr);

  k_layer2<<<NN / 4, 256, 0, stream>>>(x1h, bkt, deg, We, be, h2);

  k_mlp<1><<<mlpBlocks, 256, smem, stream>>>(h2, whi + 2 * 16384, wlo + 2 * 16384, b2a,
                                             whi + 3 * 16384, wlo + 3 * 16384, b2b,
                                             nullptr, batch, gsum);

  k_final<<<NG, HID, 0, stream>>>(gsum, pos, Wm1, bm1, Wm2, bm2, out);
}

// Round 13
// 163.991 us; speedup vs baseline: 1.5536x; 1.0363x over previous
//
#include <hip/hip_runtime.h>
#include <math.h>

#define NN 50000
#define NE 600000
#define HID 128
#define NG 64
#define CAP 48    // bucket capacity: Poisson(12) max-degree ~28; P(overflow)<1e-15
#define ASTRH 136 // LDS A-tile row stride in halves (272B): frag reads <=2-way
#define NBIN 196  // coarse bins: dst>>8, ceil(50000/256)
#define CHUNK 2344 // edges per hist/scatter block: ceil(600000/256)

using half8v = __attribute__((ext_vector_type(8))) _Float16;
using half2v = __attribute__((ext_vector_type(2))) _Float16;
using f32x4  = __attribute__((ext_vector_type(4))) float;

__device__ __forceinline__ float unpack_w(unsigned p) {
  return (float)__builtin_bit_cast(_Float16, (unsigned short)(p & 0xffffu));
}

// ---- Fused prep: pos | zero gsum | weight split | per-block bin histogram ----
// blocks [0,196): batch (sorted) boundary detection -> pos[]
// blocks [196,204): zero gsum (2048 float4)
// blocks [204,236): f32 -> f16 hi/lo weight split, fragment-linear
// blocks [236,492): LDS histogram of dst>>8 over this block's edge slice
__global__ void k_prep(const int* __restrict__ batch, float* __restrict__ gsum,
                       int* __restrict__ pos,
                       const float* __restrict__ W1a, const float* __restrict__ W1b,
                       const float* __restrict__ W2a, const float* __restrict__ W2b,
                       _Float16* __restrict__ whi, _Float16* __restrict__ wlo,
                       const int* __restrict__ dst, int* __restrict__ hist) {
  __shared__ int lh[NBIN];
  int b = blockIdx.x, t = threadIdx.x;
  if (b < 196) {
    int i = b * 256 + t;
    if (i < NN) {
      int bb = batch[i];
      if (i == 0) {
        for (int g = 0; g <= bb; ++g) pos[g] = 0;
      } else {
        int bp = batch[i - 1];
        for (int g = bp + 1; g <= bb; ++g) pos[g] = i;
      }
      if (i == NN - 1) {
        for (int g = bb + 1; g <= NG; ++g) pos[g] = NN;
      }
    }
  } else if (b < 204) {
    int i = (b - 196) * 256 + t;
    if (i < 2048) reinterpret_cast<float4*>(gsum)[i] = make_float4(0.f, 0.f, 0.f, 0.f);
  } else if (b < 236) {
    int tid = (b - 204) * 256 + t;  // 0..8191
    int m = tid >> 11;
    const float* W = (m == 0) ? W1a : (m == 1) ? W1b : (m == 2) ? W2a : W2b;
    int rem = tid & 2047;
    int kt = rem >> 9;
    int fj = (rem >> 6) & 7;
    int l = rem & 63;
    int col = fj * 16 + (l & 15);
    int kbase = kt * 32 + (l >> 4) * 8;
    size_t obase = (size_t)m * 16384 + (size_t)(((kt * 8 + fj) * 64 + l)) * 8;
#pragma unroll
    for (int j = 0; j < 8; ++j) {
      float x = W[(size_t)(kbase + j) * HID + col];
      _Float16 h = (_Float16)x;
      whi[obase + j] = h;
      wlo[obase + j] = (_Float16)(x - (float)h);
    }
  } else {
    int hb = b - 236;  // 0..255
    if (t < NBIN) lh[t] = 0;
    __syncthreads();
    int lo = hb * CHUNK, hi = min(lo + CHUNK, NE);
    for (int e = lo + t; e < hi; e += 256) atomicAdd(&lh[dst[e] >> 8], 1);
    __syncthreads();
    if (t < NBIN) hist[t * 256 + hb] = lh[t];
  }
}

// ---- Scatter: partition edges by bin (dst>>8). ZERO global atomics. ----
// Each block computes its own offsets from the L2-hot hist table (all blocks
// derive identical binbase; block 0 publishes it), then scatters its slice
// with LDS cursors. part entry = {src, (dst&255)<<16 | f16bits(ew)}.
__global__ void k_scatter(const int* __restrict__ src, const int* __restrict__ dst,
                          const float* __restrict__ ew, const int* __restrict__ hist,
                          int* __restrict__ gbinbase, int2* __restrict__ part) {
  __shared__ int ps[256];
  __shared__ int cur[NBIN];
  int b = blockIdx.x, t = threadIdx.x;
  int sum0 = 0, T = 0;
  if (t < NBIN) {
    const int* row = &hist[t * 256];
#pragma unroll 4
    for (int i = 0; i < 256; ++i) {
      int v = row[i];
      T += v;
      sum0 += (i < b) ? v : 0;
    }
  }
  ps[t] = T;
  __syncthreads();
  for (int d = 1; d < 256; d <<= 1) {
    int u = (t >= d) ? ps[t - d] : 0;
    __syncthreads();
    ps[t] += u;
    __syncthreads();
  }
  if (t < NBIN) {
    int ebase = ps[t] - T;  // exclusive bin base
    cur[t] = ebase + sum0;  // this block's start within the bin
    if (b == 0) gbinbase[t] = ebase;
  }
  if (b == 0 && t == 0) gbinbase[NBIN] = NE;
  __syncthreads();
  int lo = b * CHUNK, hi = min(lo + CHUNK, NE);
  for (int e = lo + t; e < hi; e += 256) {
    int d0 = dst[e];
    int p = atomicAdd(&cur[d0 >> 8], 1);  // LDS atomic
    _Float16 w = (_Float16)ew[e];
    unsigned wb = (unsigned)__builtin_bit_cast(unsigned short, w);
    part[p] = make_int2(src[e], ((d0 & 255) << 16) | (int)wb);
  }
}

// ---- Binfill: bin j's contiguous edges -> per-dst bucket slots (LDS cursors).
// Writes land in a 49KB bucket window per block; deg written coalesced (no
// pre-zero needed anywhere).
__global__ void k_binfill(const int2* __restrict__ part, const int* __restrict__ gbinbase,
                          unsigned* __restrict__ bkt, int* __restrict__ deg) {
  __shared__ int cur[256];
  int j = blockIdx.x, t = threadIdx.x;
  cur[t] = 0;
  __syncthreads();
  int lo = gbinbase[j], hi = gbinbase[j + 1];
  for (int e = lo + t; e < hi; e += 256) {
    int2 q = part[e];
    int dl = q.y >> 16;
    int p = atomicAdd(&cur[dl], 1);  // LDS atomic
    if (p < CAP)
      bkt[(size_t)((j << 8) + dl) * CAP + p] =
          ((unsigned)q.x << 16) | ((unsigned)q.y & 0xffffu);
  }
  __syncthreads();
  int node = (j << 8) + t;
  if (node < NN) deg[node] = cur[t];
}

// ---------------- Layer 1 aggregation (rank-1: scalars only), f16 out ----------
__global__ void k_layer1(const float* __restrict__ nw, const unsigned* __restrict__ bkt,
                         const int* __restrict__ deg,
                         const float* __restrict__ Wn, const float* __restrict__ bn,
                         const float* __restrict__ We, const float* __restrict__ be,
                         _Float16* __restrict__ h) {
  int wave = threadIdx.x >> 6;
  int lane = threadIdx.x & 63;
  int node = blockIdx.x * 4 + wave;
  if (node >= NN) return;
  int c = lane * 2;
  float wn0 = Wn[c], wn1 = Wn[c + 1];
  float we0 = We[c], we1 = We[c + 1];
  float bn0 = bn[c], bn1 = bn[c + 1];
  float cb0 = bn0 + be[c], cb1 = bn1 + be[c + 1];
  float ai = nw[node];
  float acc0 = fmaf(ai, wn0, bn0);
  float acc1 = fmaf(ai, wn1, bn1);
  int k0 = node * CAP;
  int cnt = min(deg[node], CAP);
  int k = 0;
  for (; k + 4 <= cnt; k += 4) {
    uint4 q = *reinterpret_cast<const uint4*>(&bkt[k0 + k]);
    float a0 = nw[q.x >> 16], a1 = nw[q.y >> 16];
    float a2 = nw[q.z >> 16], a3 = nw[q.w >> 16];
    float e0 = unpack_w(q.x), e1 = unpack_w(q.y);
    float e2 = unpack_w(q.z), e3 = unpack_w(q.w);
    acc0 += fmaxf(fmaf(a0, wn0, fmaf(e0, we0, cb0)), 0.f);
    acc1 += fmaxf(fmaf(a0, wn1, fmaf(e0, we1, cb1)), 0.f);
    acc0 += fmaxf(fmaf(a1, wn0, fmaf(e1, we0, cb0)), 0.f);
    acc1 += fmaxf(fmaf(a1, wn1, fmaf(e1, we1, cb1)), 0.f);
    acc0 += fmaxf(fmaf(a2, wn0, fmaf(e2, we0, cb0)), 0.f);
    acc1 += fmaxf(fmaf(a2, wn1, fmaf(e2, we1, cb1)), 0.f);
    acc0 += fmaxf(fmaf(a3, wn0, fmaf(e3, we0, cb0)), 0.f);
    acc1 += fmaxf(fmaf(a3, wn1, fmaf(e3, we1, cb1)), 0.f);
  }
  for (; k < cnt; ++k) {
    unsigned p = bkt[k0 + k];
    float a = nw[p >> 16];
    float b = unpack_w(p);
    acc0 += fmaxf(fmaf(a, wn0, fmaf(b, we0, cb0)), 0.f);
    acc1 += fmaxf(fmaf(a, wn1, fmaf(b, we1, cb1)), 0.f);
  }
  half2v o; o[0] = (_Float16)acc0; o[1] = (_Float16)acc1;
  *reinterpret_cast<half2v*>(&h[(size_t)node * HID + c]) = o;
}

// ---------------- Layer 2 aggregation: f16 gathers, 4 in flight ----------------
__global__ void k_layer2(const _Float16* __restrict__ x1, const unsigned* __restrict__ bkt,
                         const int* __restrict__ deg,
                         const float* __restrict__ We, const float* __restrict__ be,
                         _Float16* __restrict__ h) {
  int wave = threadIdx.x >> 6;
  int lane = threadIdx.x & 63;
  int node = blockIdx.x * 4 + wave;
  if (node >= NN) return;
  int c = lane * 2;
  float we0 = We[c], we1 = We[c + 1];
  float b0 = be[c], b1 = be[c + 1];
  half2v x = *reinterpret_cast<const half2v*>(&x1[(size_t)node * HID + c]);
  float acc0 = (float)x[0], acc1 = (float)x[1];
  int k0 = node * CAP;
  int cnt = min(deg[node], CAP);
  int k = 0;
  for (; k + 4 <= cnt; k += 4) {
    uint4 q = *reinterpret_cast<const uint4*>(&bkt[k0 + k]);
    half2v r0 = *reinterpret_cast<const half2v*>(&x1[(size_t)(q.x >> 16) * HID + c]);
    half2v r1 = *reinterpret_cast<const half2v*>(&x1[(size_t)(q.y >> 16) * HID + c]);
    half2v r2 = *reinterpret_cast<const half2v*>(&x1[(size_t)(q.z >> 16) * HID + c]);
    half2v r3 = *reinterpret_cast<const half2v*>(&x1[(size_t)(q.w >> 16) * HID + c]);
    float e0 = unpack_w(q.x), e1 = unpack_w(q.y);
    float e2 = unpack_w(q.z), e3 = unpack_w(q.w);
    acc0 += fmaxf((float)r0[0] + fmaf(e0, we0, b0), 0.f);
    acc1 += fmaxf((float)r0[1] + fmaf(e0, we1, b1), 0.f);
    acc0 += fmaxf((float)r1[0] + fmaf(e1, we0, b0), 0.f);
    acc1 += fmaxf((float)r1[1] + fmaf(e1, we1, b1), 0.f);
    acc0 += fmaxf((float)r2[0] + fmaf(e2, we0, b0), 0.f);
    acc1 += fmaxf((float)r2[1] + fmaf(e2, we1, b1), 0.f);
    acc0 += fmaxf((float)r3[0] + fmaf(e3, we0, b0), 0.f);
    acc1 += fmaxf((float)r3[1] + fmaf(e3, we1, b1), 0.f);
  }
  for (; k < cnt; ++k) {
    unsigned p = bkt[k0 + k];
    float b = unpack_w(p);
    half2v xs = *reinterpret_cast<const half2v*>(&x1[(size_t)(p >> 16) * HID + c]);
    acc0 += fmaxf((float)xs[0] + fmaf(b, we0, b0), 0.f);
    acc1 += fmaxf((float)xs[1] + fmaf(b, we1, b1), 0.f);
  }
  half2v o; o[0] = (_Float16)acc0; o[1] = (_Float16)acc1;
  *reinterpret_cast<half2v*>(&h[(size_t)node * HID + c]) = o;
}

// ---------------- MFMA MLP pair: Y = relu(leaky(X@Wa+ba)@Wb+bb) ----------------
template <int POOL>
__global__ __launch_bounds__(256, 4) void k_mlp(
    const _Float16* __restrict__ X,
    const _Float16* __restrict__ Wahi, const _Float16* __restrict__ Walo,
    const float* __restrict__ ba,
    const _Float16* __restrict__ Wbhi, const _Float16* __restrict__ Wblo,
    const float* __restrict__ bb,
    _Float16* __restrict__ Y,
    const int* __restrict__ batch, float* __restrict__ gsum) {
  extern __shared__ char smem_raw[];
  _Float16* Ah = (_Float16*)smem_raw;
  int* sB = (int*)(smem_raw + 128 * ASTRH * 2);
  const int tid = threadIdx.x;
  const int l = tid & 63;
  const int wrow = (tid >> 6) * 32;
  const int rowBase = blockIdx.x * 128;

  if (POOL && tid < 128) sB[tid] = batch[min(rowBase + tid, NN - 1)];

  {
    int rr = tid >> 4;
    int c0 = (tid & 15) * 8;
#pragma unroll
    for (int p = 0; p < 8; ++p) {
      int r = p * 16 + rr;
      int srcRow = min(rowBase + r, NN - 1);
      half8v v = *reinterpret_cast<const half8v*>(&X[(size_t)srcRow * HID + c0]);
      *reinterpret_cast<half8v*>(&Ah[r * ASTRH + c0]) = v;
    }
  }
  __syncthreads();

  const int arow0 = wrow + (l & 15);
  const int kgrp = (l >> 4) * 8;
  const int lcol = l & 15;

  f32x4 acc[2][8];
#pragma unroll
  for (int i = 0; i < 2; ++i)
#pragma unroll
    for (int j = 0; j < 8; ++j) acc[i][j] = f32x4{0.f, 0.f, 0.f, 0.f};

#pragma unroll
  for (int ks = 0; ks < 4; ++ks) {
    half8v a0 = *reinterpret_cast<const half8v*>(&Ah[arow0 * ASTRH + ks * 32 + kgrp]);
    half8v a1 = *reinterpret_cast<const half8v*>(&Ah[(arow0 + 16) * ASTRH + ks * 32 + kgrp]);
    const _Float16* wbh = &Wahi[(size_t)((ks * 8) * 64 + l) * 8];
    const _Float16* wbl = &Walo[(size_t)((ks * 8) * 64 + l) * 8];
#pragma unroll
    for (int fj = 0; fj < 8; ++fj) {
      half8v bh = *reinterpret_cast<const half8v*>(wbh + fj * 512);
      half8v bl = *reinterpret_cast<const half8v*>(wbl + fj * 512);
      acc[0][fj] = __builtin_amdgcn_mfma_f32_16x16x32_f16(a0, bh, acc[0][fj], 0, 0, 0);
      acc[0][fj] = __builtin_amdgcn_mfma_f32_16x16x32_f16(a0, bl, acc[0][fj], 0, 0, 0);
      acc[1][fj] = __builtin_amdgcn_mfma_f32_16x16x32_f16(a1, bh, acc[1][fj], 0, 0, 0);
      acc[1][fj] = __builtin_amdgcn_mfma_f32_16x16x32_f16(a1, bl, acc[1][fj], 0, 0, 0);
    }
  }

  {
    float bal[8];
#pragma unroll
    for (int fj = 0; fj < 8; ++fj) bal[fj] = ba[fj * 16 + lcol];
#pragma unroll
    for (int fi = 0; fi < 2; ++fi) {
      int rbase = wrow + fi * 16 + ((l >> 4) << 2);
#pragma unroll
      for (int fj = 0; fj < 8; ++fj) {
#pragma unroll
        for (int r = 0; r < 4; ++r) {
          float v = acc[fi][fj][r] + bal[fj];
          v = (v > 0.f) ? v : 0.01f * v;
          Ah[(rbase + r) * ASTRH + fj * 16 + lcol] = (_Float16)v;
        }
      }
    }
  }

  f32x4 acc2[2][8];
#pragma unroll
  for (int i = 0; i < 2; ++i)
#pragma unroll
    for (int j = 0; j < 8; ++j) acc2[i][j] = f32x4{0.f, 0.f, 0.f, 0.f};

#pragma unroll
  for (int ks = 0; ks < 4; ++ks) {
    half8v a0 = *reinterpret_cast<const half8v*>(&Ah[arow0 * ASTRH + ks * 32 + kgrp]);
    half8v a1 = *reinterpret_cast<const half8v*>(&Ah[(arow0 + 16) * ASTRH + ks * 32 + kgrp]);
    const _Float16* wbh = &Wbhi[(size_t)((ks * 8) * 64 + l) * 8];
    const _Float16* wbl = &Wblo[(size_t)((ks * 8) * 64 + l) * 8];
#pragma unroll
    for (int fj = 0; fj < 8; ++fj) {
      half8v bh = *reinterpret_cast<const half8v*>(wbh + fj * 512);
      half8v bl = *reinterpret_cast<const half8v*>(wbl + fj * 512);
      acc2[0][fj] = __builtin_amdgcn_mfma_f32_16x16x32_f16(a0, bh, acc2[0][fj], 0, 0, 0);
      acc2[0][fj] = __builtin_amdgcn_mfma_f32_16x16x32_f16(a0, bl, acc2[0][fj], 0, 0, 0);
      acc2[1][fj] = __builtin_amdgcn_mfma_f32_16x16x32_f16(a1, bh, acc2[1][fj], 0, 0, 0);
      acc2[1][fj] = __builtin_amdgcn_mfma_f32_16x16x32_f16(a1, bl, acc2[1][fj], 0, 0, 0);
    }
  }

  float bbl[8];
#pragma unroll
  for (int fj = 0; fj < 8; ++fj) bbl[fj] = bb[fj * 16 + lcol];

  if (!POOL) {
#pragma unroll
    for (int fi = 0; fi < 2; ++fi) {
      int rbase = wrow + fi * 16 + ((l >> 4) << 2);
#pragma unroll
      for (int fj = 0; fj < 8; ++fj) {
#pragma unroll
        for (int r = 0; r < 4; ++r) {
          int row = rowBase + rbase + r;
          if (row < NN)
            Y[(size_t)row * HID + fj * 16 + lcol] =
                (_Float16)fmaxf(acc2[fi][fj][r] + bbl[fj], 0.f);
        }
      }
    }
  } else {
    __syncthreads();
    _Float16* sPh = (_Float16*)smem_raw;
#pragma unroll
    for (int fi = 0; fi < 2; ++fi) {
      int rbase = wrow + fi * 16 + ((l >> 4) << 2);
#pragma unroll
      for (int fj = 0; fj < 8; ++fj) {
#pragma unroll
        for (int r = 0; r < 4; ++r) {
          bool ok = (rowBase + rbase + r) < NN;
          float z = fmaxf(acc2[fi][fj][r] + bbl[fj], 0.f);
          sPh[(rbase + r) * 132 + fj * 16 + lcol] = (_Float16)(ok ? z : 0.f);
        }
      }
    }
    __syncthreads();
    if (tid < HID) {
      int cur = sB[0];
      float run = 0.f;
      for (int r = 0; r < 128; ++r) {
        int g = sB[r];
        if (g != cur) {
          atomicAdd(&gsum[cur * HID + tid], run);
          run = 0.f; cur = g;
        }
        run += (float)sPh[r * 132 + tid];
      }
      atomicAdd(&gsum[cur * HID + tid], run);
    }
  }
}

// ---------------- Final: pooled MLP -> sigmoid ----------------
__global__ void k_final(const float* __restrict__ gsum, const int* __restrict__ pos,
                        const float* __restrict__ Wm1, const float* __restrict__ bm1,
                        const float* __restrict__ Wm2, const float* __restrict__ bm2,
                        float* __restrict__ out) {
  __shared__ float sp[HID];
  __shared__ float red[HID];
  int g = blockIdx.x;
  int k = threadIdx.x;  // 128 threads
  float c = fmaxf((float)(pos[g + 1] - pos[g]), 1.f);
  sp[k] = gsum[g * HID + k] / c;
  __syncthreads();
  float dot = 0.f;
  for (int j = 0; j < HID; ++j) dot = fmaf(sp[j], Wm1[j * HID + k], dot);
  float z = dot + bm1[k];
  z = (z > 0.f) ? z : 0.01f * z;
  red[k] = z * Wm2[k];
  __syncthreads();
  for (int s = 64; s > 0; s >>= 1) {
    if (k < s) red[k] += red[k + s];
    __syncthreads();
  }
  if (k == 0) out[g] = 1.f / (1.f + expf(-(red[0] + bm2[0])));
}

extern "C" void kernel_launch(void* const* d_in, const int* in_sizes, int n_in,
                              void* d_out, int out_size, void* d_ws, size_t ws_size,
                              hipStream_t stream) {
  const float* nw = (const float*)d_in[0];
  const float* ew = (const float*)d_in[1];
  const int* ei = (const int*)d_in[2];
  const int* src = ei;
  const int* dst = ei + NE;
  const int* batch = (const int*)d_in[3];
  const float* Wn = (const float*)d_in[4];
  const float* bn = (const float*)d_in[5];
  const float* We = (const float*)d_in[6];
  const float* be = (const float*)d_in[7];
  const float* W1a = (const float*)d_in[8];
  const float* b1a = (const float*)d_in[9];
  const float* W1b = (const float*)d_in[10];
  const float* b1b = (const float*)d_in[11];
  const float* W2a = (const float*)d_in[12];
  const float* b2a = (const float*)d_in[13];
  const float* W2b = (const float*)d_in[14];
  const float* b2b = (const float*)d_in[15];
  const float* Wm1 = (const float*)d_in[16];
  const float* bm1 = (const float*)d_in[17];
  const float* Wm2 = (const float*)d_in[18];
  const float* bm2 = (const float*)d_in[19];
  float* out = (float*)d_out;

  char* ws = (char*)d_ws;
  size_t o = 0;
  auto alloc = [&](size_t b) {
    size_t p = o;
    o += (b + 255) & ~(size_t)255;
    return p;
  };
  size_t deg_o = alloc(NN * 4);                 // written by binfill (no pre-zero)
  size_t gsum_o = alloc((size_t)NG * HID * 4);
  size_t pos_o = alloc((NG + 1) * 4);
  size_t hist_o = alloc((size_t)NBIN * 256 * 4);
  size_t gbb_o = alloc((NBIN + 1) * 4);
  size_t part_o = alloc((size_t)NE * 8);        // bin-partitioned edges
  size_t bkt_o = alloc((size_t)NN * CAP * 4);   // packed-u32 bucketed CSR
  size_t h1_o = alloc((size_t)NN * HID * 2);
  size_t x1_o = alloc((size_t)NN * HID * 2);
  size_t h2_o = alloc((size_t)NN * HID * 2);
  size_t whi_o = alloc((size_t)4 * 16384 * 2);
  size_t wlo_o = alloc((size_t)4 * 16384 * 2);

  int* deg = (int*)(ws + deg_o);
  float* gsum = (float*)(ws + gsum_o);
  int* pos = (int*)(ws + pos_o);
  int* hist = (int*)(ws + hist_o);
  int* gbinbase = (int*)(ws + gbb_o);
  int2* part = (int2*)(ws + part_o);
  unsigned* bkt = (unsigned*)(ws + bkt_o);
  _Float16* h1 = (_Float16*)(ws + h1_o);
  _Float16* x1h = (_Float16*)(ws + x1_o);
  _Float16* h2 = (_Float16*)(ws + h2_o);
  _Float16* whi = (_Float16*)(ws + whi_o);
  _Float16* wlo = (_Float16*)(ws + wlo_o);

  // 8 dispatches, ZERO global atomics in the CSR build
  k_prep<<<492, 256, 0, stream>>>(batch, gsum, pos, W1a, W1b, W2a, W2b, whi, wlo,
                                  dst, hist);
  k_scatter<<<256, 256, 0, stream>>>(src, dst, ew, hist, gbinbase, part);
  k_binfill<<<NBIN, 256, 0, stream>>>(part, gbinbase, bkt, deg);

  k_layer1<<<NN / 4, 256, 0, stream>>>(nw, bkt, deg, Wn, bn, We, be, h1);

  size_t smem = (size_t)128 * ASTRH * 2 + 512;  // 35,328 B -> 4 blocks/CU
  const int mlpBlocks = (NN + 127) / 128;  // 391
  k_mlp<0><<<mlpBlocks, 256, smem, stream>>>(h1, whi, wlo, b1a,
                                             whi + 16384, wlo + 16384, b1b,
                                             x1h, nullptr, nullptr);

  k_layer2<<<NN / 4, 256, 0, stream>>>(x1h, bkt, deg, We, be, h2);

  k_mlp<1><<<mlpBlocks, 256, smem, stream>>>(h2, whi + 2 * 16384, wlo + 2 * 16384, b2a,
                                             whi + 3 * 16384, wlo + 3 * 16384, b2b,
                                             nullptr, batch, gsum);

  k_final<<<NG, HID, 0, stream>>>(gsum, pos, Wm1, bm1, Wm2, bm2, out);
}

// Round 14
// 140.894 us; speedup vs baseline: 1.8083x; 1.1639x over previous
//
#include <hip/hip_runtime.h>
#include <math.h>

#define NN 50000
#define NE 600000
#define HID 128
#define NG 64
#define CAP 48    // bucket capacity: Poisson(12) max-degree ~28; P(overflow)<1e-15
#define ASTRH 136 // LDS A-tile row stride in halves (272B): frag reads <=2-way
#define NBIN 196  // coarse bins: dst>>8, ceil(50000/256)
#define CHUNK 2344 // edges per hist/scatter block: ceil(600000/256)

using half8v = __attribute__((ext_vector_type(8))) _Float16;
using half2v = __attribute__((ext_vector_type(2))) _Float16;
using f32x4  = __attribute__((ext_vector_type(4))) float;

__device__ __forceinline__ float unpack_w(unsigned p) {
  return (float)__builtin_bit_cast(_Float16, (unsigned short)(p & 0xffffu));
}

// ---- Fused prep: pos | zero gsum | weight cast | per-block bin histogram ----
// blocks [0,196): batch (sorted) boundary detection -> pos[]
// blocks [196,204): zero gsum (2048 float4)
// blocks [204,236): f32 -> f16 weight cast, fragment-linear (single f16; the
//   lo-correction term was dropped in R14 -- W err ~2^-11 rel, same class as
//   the f16 feature interfaces that have held absmax ~0)
// blocks [236,492): LDS histogram of dst>>8 over this block's edge slice
__global__ void k_prep(const int* __restrict__ batch, float* __restrict__ gsum,
                       int* __restrict__ pos,
                       const float* __restrict__ W1a, const float* __restrict__ W1b,
                       const float* __restrict__ W2a, const float* __restrict__ W2b,
                       _Float16* __restrict__ whi,
                       const int* __restrict__ dst, int* __restrict__ hist) {
  __shared__ int lh[NBIN];
  int b = blockIdx.x, t = threadIdx.x;
  if (b < 196) {
    int i = b * 256 + t;
    if (i < NN) {
      int bb = batch[i];
      if (i == 0) {
        for (int g = 0; g <= bb; ++g) pos[g] = 0;
      } else {
        int bp = batch[i - 1];
        for (int g = bp + 1; g <= bb; ++g) pos[g] = i;
      }
      if (i == NN - 1) {
        for (int g = bb + 1; g <= NG; ++g) pos[g] = NN;
      }
    }
  } else if (b < 204) {
    int i = (b - 196) * 256 + t;
    if (i < 2048) reinterpret_cast<float4*>(gsum)[i] = make_float4(0.f, 0.f, 0.f, 0.f);
  } else if (b < 236) {
    int tid = (b - 204) * 256 + t;  // 0..8191
    int m = tid >> 11;
    const float* W = (m == 0) ? W1a : (m == 1) ? W1b : (m == 2) ? W2a : W2b;
    int rem = tid & 2047;
    int kt = rem >> 9;
    int fj = (rem >> 6) & 7;
    int l = rem & 63;
    int col = fj * 16 + (l & 15);
    int kbase = kt * 32 + (l >> 4) * 8;
    size_t obase = (size_t)m * 16384 + (size_t)(((kt * 8 + fj) * 64 + l)) * 8;
#pragma unroll
    for (int j = 0; j < 8; ++j) {
      whi[obase + j] = (_Float16)W[(size_t)(kbase + j) * HID + col];
    }
  } else {
    int hb = b - 236;  // 0..255
    if (t < NBIN) lh[t] = 0;
    __syncthreads();
    int lo = hb * CHUNK, hi = min(lo + CHUNK, NE);
    for (int e = lo + t; e < hi; e += 256) atomicAdd(&lh[dst[e] >> 8], 1);
    __syncthreads();
    if (t < NBIN) hist[t * 256 + hb] = lh[t];
  }
}

// ---- Scatter: partition edges by bin (dst>>8). ZERO global atomics. ----
__global__ void k_scatter(const int* __restrict__ src, const int* __restrict__ dst,
                          const float* __restrict__ ew, const int* __restrict__ hist,
                          int* __restrict__ gbinbase, int2* __restrict__ part) {
  __shared__ int ps[256];
  __shared__ int cur[NBIN];
  int b = blockIdx.x, t = threadIdx.x;
  int sum0 = 0, T = 0;
  if (t < NBIN) {
    const int* row = &hist[t * 256];
#pragma unroll 4
    for (int i = 0; i < 256; ++i) {
      int v = row[i];
      T += v;
      sum0 += (i < b) ? v : 0;
    }
  }
  ps[t] = T;
  __syncthreads();
  for (int d = 1; d < 256; d <<= 1) {
    int u = (t >= d) ? ps[t - d] : 0;
    __syncthreads();
    ps[t] += u;
    __syncthreads();
  }
  if (t < NBIN) {
    int ebase = ps[t] - T;
    cur[t] = ebase + sum0;
    if (b == 0) gbinbase[t] = ebase;
  }
  if (b == 0 && t == 0) gbinbase[NBIN] = NE;
  __syncthreads();
  int lo = b * CHUNK, hi = min(lo + CHUNK, NE);
  for (int e = lo + t; e < hi; e += 256) {
    int d0 = dst[e];
    int p = atomicAdd(&cur[d0 >> 8], 1);  // LDS atomic
    _Float16 w = (_Float16)ew[e];
    unsigned wb = (unsigned)__builtin_bit_cast(unsigned short, w);
    part[p] = make_int2(src[e], ((d0 & 255) << 16) | (int)wb);
  }
}

// ---- Binfill: bin j's contiguous edges -> per-dst bucket slots (LDS cursors).
__global__ void k_binfill(const int2* __restrict__ part, const int* __restrict__ gbinbase,
                          unsigned* __restrict__ bkt, int* __restrict__ deg) {
  __shared__ int cur[256];
  int j = blockIdx.x, t = threadIdx.x;
  cur[t] = 0;
  __syncthreads();
  int lo = gbinbase[j], hi = gbinbase[j + 1];
  for (int e = lo + t; e < hi; e += 256) {
    int2 q = part[e];
    int dl = q.y >> 16;
    int p = atomicAdd(&cur[dl], 1);  // LDS atomic
    if (p < CAP)
      bkt[(size_t)((j << 8) + dl) * CAP + p] =
          ((unsigned)q.x << 16) | ((unsigned)q.y & 0xffffu);
  }
  __syncthreads();
  int node = (j << 8) + t;
  if (node < NN) deg[node] = cur[t];
}

// ---------------- Layer 1 aggregation (rank-1: scalars only), f16 out ----------
__global__ void k_layer1(const float* __restrict__ nw, const unsigned* __restrict__ bkt,
                         const int* __restrict__ deg,
                         const float* __restrict__ Wn, const float* __restrict__ bn,
                         const float* __restrict__ We, const float* __restrict__ be,
                         _Float16* __restrict__ h) {
  int wave = threadIdx.x >> 6;
  int lane = threadIdx.x & 63;
  int node = blockIdx.x * 4 + wave;
  if (node >= NN) return;
  int c = lane * 2;
  float wn0 = Wn[c], wn1 = Wn[c + 1];
  float we0 = We[c], we1 = We[c + 1];
  float bn0 = bn[c], bn1 = bn[c + 1];
  float cb0 = bn0 + be[c], cb1 = bn1 + be[c + 1];
  float ai = nw[node];
  float acc0 = fmaf(ai, wn0, bn0);
  float acc1 = fmaf(ai, wn1, bn1);
  int k0 = node * CAP;
  int cnt = min(deg[node], CAP);
  int k = 0;
  for (; k + 4 <= cnt; k += 4) {
    uint4 q = *reinterpret_cast<const uint4*>(&bkt[k0 + k]);
    float a0 = nw[q.x >> 16], a1 = nw[q.y >> 16];
    float a2 = nw[q.z >> 16], a3 = nw[q.w >> 16];
    float e0 = unpack_w(q.x), e1 = unpack_w(q.y);
    float e2 = unpack_w(q.z), e3 = unpack_w(q.w);
    acc0 += fmaxf(fmaf(a0, wn0, fmaf(e0, we0, cb0)), 0.f);
    acc1 += fmaxf(fmaf(a0, wn1, fmaf(e0, we1, cb1)), 0.f);
    acc0 += fmaxf(fmaf(a1, wn0, fmaf(e1, we0, cb0)), 0.f);
    acc1 += fmaxf(fmaf(a1, wn1, fmaf(e1, we1, cb1)), 0.f);
    acc0 += fmaxf(fmaf(a2, wn0, fmaf(e2, we0, cb0)), 0.f);
    acc1 += fmaxf(fmaf(a2, wn1, fmaf(e2, we1, cb1)), 0.f);
    acc0 += fmaxf(fmaf(a3, wn0, fmaf(e3, we0, cb0)), 0.f);
    acc1 += fmaxf(fmaf(a3, wn1, fmaf(e3, we1, cb1)), 0.f);
  }
  for (; k < cnt; ++k) {
    unsigned p = bkt[k0 + k];
    float a = nw[p >> 16];
    float b = unpack_w(p);
    acc0 += fmaxf(fmaf(a, wn0, fmaf(b, we0, cb0)), 0.f);
    acc1 += fmaxf(fmaf(a, wn1, fmaf(b, we1, cb1)), 0.f);
  }
  half2v o; o[0] = (_Float16)acc0; o[1] = (_Float16)acc1;
  *reinterpret_cast<half2v*>(&h[(size_t)node * HID + c]) = o;
}

// ---------------- Layer 2 aggregation: f16 gathers, 8 in flight ----------------
__global__ void k_layer2(const _Float16* __restrict__ x1, const unsigned* __restrict__ bkt,
                         const int* __restrict__ deg,
                         const float* __restrict__ We, const float* __restrict__ be,
                         _Float16* __restrict__ h) {
  int wave = threadIdx.x >> 6;
  int lane = threadIdx.x & 63;
  int node = blockIdx.x * 4 + wave;
  if (node >= NN) return;
  int c = lane * 2;
  float we0 = We[c], we1 = We[c + 1];
  float b0 = be[c], b1 = be[c + 1];
  half2v x = *reinterpret_cast<const half2v*>(&x1[(size_t)node * HID + c]);
  float acc0 = (float)x[0], acc1 = (float)x[1];
  int k0 = node * CAP;
  int cnt = min(deg[node], CAP);
  int k = 0;
  for (; k + 8 <= cnt; k += 8) {  // 8 independent 256B row gathers in flight
    uint4 qa = *reinterpret_cast<const uint4*>(&bkt[k0 + k]);
    uint4 qb = *reinterpret_cast<const uint4*>(&bkt[k0 + k + 4]);
    half2v r0 = *reinterpret_cast<const half2v*>(&x1[(size_t)(qa.x >> 16) * HID + c]);
    half2v r1 = *reinterpret_cast<const half2v*>(&x1[(size_t)(qa.y >> 16) * HID + c]);
    half2v r2 = *reinterpret_cast<const half2v*>(&x1[(size_t)(qa.z >> 16) * HID + c]);
    half2v r3 = *reinterpret_cast<const half2v*>(&x1[(size_t)(qa.w >> 16) * HID + c]);
    half2v r4 = *reinterpret_cast<const half2v*>(&x1[(size_t)(qb.x >> 16) * HID + c]);
    half2v r5 = *reinterpret_cast<const half2v*>(&x1[(size_t)(qb.y >> 16) * HID + c]);
    half2v r6 = *reinterpret_cast<const half2v*>(&x1[(size_t)(qb.z >> 16) * HID + c]);
    half2v r7 = *reinterpret_cast<const half2v*>(&x1[(size_t)(qb.w >> 16) * HID + c]);
    float e0 = unpack_w(qa.x), e1 = unpack_w(qa.y);
    float e2 = unpack_w(qa.z), e3 = unpack_w(qa.w);
    float e4 = unpack_w(qb.x), e5 = unpack_w(qb.y);
    float e6 = unpack_w(qb.z), e7 = unpack_w(qb.w);
    acc0 += fmaxf((float)r0[0] + fmaf(e0, we0, b0), 0.f);
    acc1 += fmaxf((float)r0[1] + fmaf(e0, we1, b1), 0.f);
    acc0 += fmaxf((float)r1[0] + fmaf(e1, we0, b0), 0.f);
    acc1 += fmaxf((float)r1[1] + fmaf(e1, we1, b1), 0.f);
    acc0 += fmaxf((float)r2[0] + fmaf(e2, we0, b0), 0.f);
    acc1 += fmaxf((float)r2[1] + fmaf(e2, we1, b1), 0.f);
    acc0 += fmaxf((float)r3[0] + fmaf(e3, we0, b0), 0.f);
    acc1 += fmaxf((float)r3[1] + fmaf(e3, we1, b1), 0.f);
    acc0 += fmaxf((float)r4[0] + fmaf(e4, we0, b0), 0.f);
    acc1 += fmaxf((float)r4[1] + fmaf(e4, we1, b1), 0.f);
    acc0 += fmaxf((float)r5[0] + fmaf(e5, we0, b0), 0.f);
    acc1 += fmaxf((float)r5[1] + fmaf(e5, we1, b1), 0.f);
    acc0 += fmaxf((float)r6[0] + fmaf(e6, we0, b0), 0.f);
    acc1 += fmaxf((float)r6[1] + fmaf(e6, we1, b1), 0.f);
    acc0 += fmaxf((float)r7[0] + fmaf(e7, we0, b0), 0.f);
    acc1 += fmaxf((float)r7[1] + fmaf(e7, we1, b1), 0.f);
  }
  for (; k + 4 <= cnt; k += 4) {
    uint4 q = *reinterpret_cast<const uint4*>(&bkt[k0 + k]);
    half2v r0 = *reinterpret_cast<const half2v*>(&x1[(size_t)(q.x >> 16) * HID + c]);
    half2v r1 = *reinterpret_cast<const half2v*>(&x1[(size_t)(q.y >> 16) * HID + c]);
    half2v r2 = *reinterpret_cast<const half2v*>(&x1[(size_t)(q.z >> 16) * HID + c]);
    half2v r3 = *reinterpret_cast<const half2v*>(&x1[(size_t)(q.w >> 16) * HID + c]);
    float e0 = unpack_w(q.x), e1 = unpack_w(q.y);
    float e2 = unpack_w(q.z), e3 = unpack_w(q.w);
    acc0 += fmaxf((float)r0[0] + fmaf(e0, we0, b0), 0.f);
    acc1 += fmaxf((float)r0[1] + fmaf(e0, we1, b1), 0.f);
    acc0 += fmaxf((float)r1[0] + fmaf(e1, we0, b0), 0.f);
    acc1 += fmaxf((float)r1[1] + fmaf(e1, we1, b1), 0.f);
    acc0 += fmaxf((float)r2[0] + fmaf(e2, we0, b0), 0.f);
    acc1 += fmaxf((float)r2[1] + fmaf(e2, we1, b1), 0.f);
    acc0 += fmaxf((float)r3[0] + fmaf(e3, we0, b0), 0.f);
    acc1 += fmaxf((float)r3[1] + fmaf(e3, we1, b1), 0.f);
  }
  for (; k < cnt; ++k) {
    unsigned p = bkt[k0 + k];
    float b = unpack_w(p);
    half2v xs = *reinterpret_cast<const half2v*>(&x1[(size_t)(p >> 16) * HID + c]);
    acc0 += fmaxf((float)xs[0] + fmaf(b, we0, b0), 0.f);
    acc1 += fmaxf((float)xs[1] + fmaf(b, we1, b1), 0.f);
  }
  half2v o; o[0] = (_Float16)acc0; o[1] = (_Float16)acc1;
  *reinterpret_cast<half2v*>(&h[(size_t)node * HID + c]) = o;
}

// ---------------- MFMA MLP pair: Y = relu(leaky(X@Wa+ba)@Wb+bb) ----------------
// X and W both f16 -> single MFMA per fragment (R14: dropped B-lo term; halves
// MFMA count and the L2 W-fragment latency chains).
template <int POOL>
__global__ __launch_bounds__(256, 4) void k_mlp(
    const _Float16* __restrict__ X,
    const _Float16* __restrict__ Wah, const float* __restrict__ ba,
    const _Float16* __restrict__ Wbh, const float* __restrict__ bb,
    _Float16* __restrict__ Y,
    const int* __restrict__ batch, float* __restrict__ gsum) {
  extern __shared__ char smem_raw[];
  _Float16* Ah = (_Float16*)smem_raw;
  int* sB = (int*)(smem_raw + 128 * ASTRH * 2);
  const int tid = threadIdx.x;
  const int l = tid & 63;
  const int wrow = (tid >> 6) * 32;
  const int rowBase = blockIdx.x * 128;

  if (POOL && tid < 128) sB[tid] = batch[min(rowBase + tid, NN - 1)];

  {
    int rr = tid >> 4;
    int c0 = (tid & 15) * 8;
#pragma unroll
    for (int p = 0; p < 8; ++p) {
      int r = p * 16 + rr;
      int srcRow = min(rowBase + r, NN - 1);
      half8v v = *reinterpret_cast<const half8v*>(&X[(size_t)srcRow * HID + c0]);
      *reinterpret_cast<half8v*>(&Ah[r * ASTRH + c0]) = v;
    }
  }
  __syncthreads();

  const int arow0 = wrow + (l & 15);
  const int kgrp = (l >> 4) * 8;
  const int lcol = l & 15;

  f32x4 acc[2][8];
#pragma unroll
  for (int i = 0; i < 2; ++i)
#pragma unroll
    for (int j = 0; j < 8; ++j) acc[i][j] = f32x4{0.f, 0.f, 0.f, 0.f};

#pragma unroll
  for (int ks = 0; ks < 4; ++ks) {
    half8v a0 = *reinterpret_cast<const half8v*>(&Ah[arow0 * ASTRH + ks * 32 + kgrp]);
    half8v a1 = *reinterpret_cast<const half8v*>(&Ah[(arow0 + 16) * ASTRH + ks * 32 + kgrp]);
    const _Float16* wbh = &Wah[(size_t)((ks * 8) * 64 + l) * 8];
#pragma unroll
    for (int fj = 0; fj < 8; ++fj) {
      half8v bh = *reinterpret_cast<const half8v*>(wbh + fj * 512);
      acc[0][fj] = __builtin_amdgcn_mfma_f32_16x16x32_f16(a0, bh, acc[0][fj], 0, 0, 0);
      acc[1][fj] = __builtin_amdgcn_mfma_f32_16x16x32_f16(a1, bh, acc[1][fj], 0, 0, 0);
    }
  }

  {
    float bal[8];
#pragma unroll
    for (int fj = 0; fj < 8; ++fj) bal[fj] = ba[fj * 16 + lcol];
#pragma unroll
    for (int fi = 0; fi < 2; ++fi) {
      int rbase = wrow + fi * 16 + ((l >> 4) << 2);
#pragma unroll
      for (int fj = 0; fj < 8; ++fj) {
#pragma unroll
        for (int r = 0; r < 4; ++r) {
          float v = acc[fi][fj][r] + bal[fj];
          v = (v > 0.f) ? v : 0.01f * v;
          Ah[(rbase + r) * ASTRH + fj * 16 + lcol] = (_Float16)v;
        }
      }
    }
  }

  f32x4 acc2[2][8];
#pragma unroll
  for (int i = 0; i < 2; ++i)
#pragma unroll
    for (int j = 0; j < 8; ++j) acc2[i][j] = f32x4{0.f, 0.f, 0.f, 0.f};

#pragma unroll
  for (int ks = 0; ks < 4; ++ks) {
    half8v a0 = *reinterpret_cast<const half8v*>(&Ah[arow0 * ASTRH + ks * 32 + kgrp]);
    half8v a1 = *reinterpret_cast<const half8v*>(&Ah[(arow0 + 16) * ASTRH + ks * 32 + kgrp]);
    const _Float16* wbh = &Wbh[(size_t)((ks * 8) * 64 + l) * 8];
#pragma unroll
    for (int fj = 0; fj < 8; ++fj) {
      half8v bh = *reinterpret_cast<const half8v*>(wbh + fj * 512);
      acc2[0][fj] = __builtin_amdgcn_mfma_f32_16x16x32_f16(a0, bh, acc2[0][fj], 0, 0, 0);
      acc2[1][fj] = __builtin_amdgcn_mfma_f32_16x16x32_f16(a1, bh, acc2[1][fj], 0, 0, 0);
    }
  }

  float bbl[8];
#pragma unroll
  for (int fj = 0; fj < 8; ++fj) bbl[fj] = bb[fj * 16 + lcol];

  if (!POOL) {
#pragma unroll
    for (int fi = 0; fi < 2; ++fi) {
      int rbase = wrow + fi * 16 + ((l >> 4) << 2);
#pragma unroll
      for (int fj = 0; fj < 8; ++fj) {
#pragma unroll
        for (int r = 0; r < 4; ++r) {
          int row = rowBase + rbase + r;
          if (row < NN)
            Y[(size_t)row * HID + fj * 16 + lcol] =
                (_Float16)fmaxf(acc2[fi][fj][r] + bbl[fj], 0.f);
        }
      }
    }
  } else {
    __syncthreads();
    _Float16* sPh = (_Float16*)smem_raw;
#pragma unroll
    for (int fi = 0; fi < 2; ++fi) {
      int rbase = wrow + fi * 16 + ((l >> 4) << 2);
#pragma unroll
      for (int fj = 0; fj < 8; ++fj) {
#pragma unroll
        for (int r = 0; r < 4; ++r) {
          bool ok = (rowBase + rbase + r) < NN;
          float z = fmaxf(acc2[fi][fj][r] + bbl[fj], 0.f);
          sPh[(rbase + r) * 132 + fj * 16 + lcol] = (_Float16)(ok ? z : 0.f);
        }
      }
    }
    __syncthreads();
    if (tid < HID) {
      int cur = sB[0];
      float run = 0.f;
      for (int r = 0; r < 128; ++r) {
        int g = sB[r];
        if (g != cur) {
          atomicAdd(&gsum[cur * HID + tid], run);
          run = 0.f; cur = g;
        }
        run += (float)sPh[r * 132 + tid];
      }
      atomicAdd(&gsum[cur * HID + tid], run);
    }
  }
}

// ---------------- Final: pooled MLP -> sigmoid ----------------
__global__ void k_final(const float* __restrict__ gsum, const int* __restrict__ pos,
                        const float* __restrict__ Wm1, const float* __restrict__ bm1,
                        const float* __restrict__ Wm2, const float* __restrict__ bm2,
                        float* __restrict__ out) {
  __shared__ float sp[HID];
  __shared__ float red[HID];
  int g = blockIdx.x;
  int k = threadIdx.x;  // 128 threads
  float c = fmaxf((float)(pos[g + 1] - pos[g]), 1.f);
  sp[k] = gsum[g * HID + k] / c;
  __syncthreads();
  float dot = 0.f;
  for (int j = 0; j < HID; ++j) dot = fmaf(sp[j], Wm1[j * HID + k], dot);
  float z = dot + bm1[k];
  z = (z > 0.f) ? z : 0.01f * z;
  red[k] = z * Wm2[k];
  __syncthreads();
  for (int s = 64; s > 0; s >>= 1) {
    if (k < s) red[k] += red[k + s];
    __syncthreads();
  }
  if (k == 0) out[g] = 1.f / (1.f + expf(-(red[0] + bm2[0])));
}

extern "C" void kernel_launch(void* const* d_in, const int* in_sizes, int n_in,
                              void* d_out, int out_size, void* d_ws, size_t ws_size,
                              hipStream_t stream) {
  const float* nw = (const float*)d_in[0];
  const float* ew = (const float*)d_in[1];
  const int* ei = (const int*)d_in[2];
  const int* src = ei;
  const int* dst = ei + NE;
  const int* batch = (const int*)d_in[3];
  const float* Wn = (const float*)d_in[4];
  const float* bn = (const float*)d_in[5];
  const float* We = (const float*)d_in[6];
  const float* be = (const float*)d_in[7];
  const float* W1a = (const float*)d_in[8];
  const float* b1a = (const float*)d_in[9];
  const float* W1b = (const float*)d_in[10];
  const float* b1b = (const float*)d_in[11];
  const float* W2a = (const float*)d_in[12];
  const float* b2a = (const float*)d_in[13];
  const float* W2b = (const float*)d_in[14];
  const float* b2b = (const float*)d_in[15];
  const float* Wm1 = (const float*)d_in[16];
  const float* bm1 = (const float*)d_in[17];
  const float* Wm2 = (const float*)d_in[18];
  const float* bm2 = (const float*)d_in[19];
  float* out = (float*)d_out;

  char* ws = (char*)d_ws;
  size_t o = 0;
  auto alloc = [&](size_t b) {
    size_t p = o;
    o += (b + 255) & ~(size_t)255;
    return p;
  };
  size_t deg_o = alloc(NN * 4);                 // written by binfill (no pre-zero)
  size_t gsum_o = alloc((size_t)NG * HID * 4);
  size_t pos_o = alloc((NG + 1) * 4);
  size_t hist_o = alloc((size_t)NBIN * 256 * 4);
  size_t gbb_o = alloc((NBIN + 1) * 4);
  size_t part_o = alloc((size_t)NE * 8);        // bin-partitioned edges
  size_t bkt_o = alloc((size_t)NN * CAP * 4);   // packed-u32 bucketed CSR
  size_t h1_o = alloc((size_t)NN * HID * 2);
  size_t x1_o = alloc((size_t)NN * HID * 2);
  size_t h2_o = alloc((size_t)NN * HID * 2);
  size_t whi_o = alloc((size_t)4 * 16384 * 2);  // f16, 4 matrices frag-linear

  int* deg = (int*)(ws + deg_o);
  float* gsum = (float*)(ws + gsum_o);
  int* pos = (int*)(ws + pos_o);
  int* hist = (int*)(ws + hist_o);
  int* gbinbase = (int*)(ws + gbb_o);
  int2* part = (int2*)(ws + part_o);
  unsigned* bkt = (unsigned*)(ws + bkt_o);
  _Float16* h1 = (_Float16*)(ws + h1_o);
  _Float16* x1h = (_Float16*)(ws + x1_o);
  _Float16* h2 = (_Float16*)(ws + h2_o);
  _Float16* whi = (_Float16*)(ws + whi_o);

  // 8 dispatches, zero global atomics in the CSR build
  k_prep<<<492, 256, 0, stream>>>(batch, gsum, pos, W1a, W1b, W2a, W2b, whi,
                                  dst, hist);
  k_scatter<<<256, 256, 0, stream>>>(src, dst, ew, hist, gbinbase, part);
  k_binfill<<<NBIN, 256, 0, stream>>>(part, gbinbase, bkt, deg);

  k_layer1<<<NN / 4, 256, 0, stream>>>(nw, bkt, deg, Wn, bn, We, be, h1);

  size_t smem = (size_t)128 * ASTRH * 2 + 512;  // 35,328 B -> 4 blocks/CU
  const int mlpBlocks = (NN + 127) / 128;  // 391
  k_mlp<0><<<mlpBlocks, 256, smem, stream>>>(h1, whi, b1a, whi + 16384, b1b,
                                             x1h, nullptr, nullptr);

  k_layer2<<<NN / 4, 256, 0, stream>>>(x1h, bkt, deg, We, be, h2);

  k_mlp<1><<<mlpBlocks, 256, smem, stream>>>(h2, whi + 2 * 16384, b2a,
                                             whi + 3 * 16384, b2b,
                                             nullptr, batch, gsum);

  k_final<<<NG, HID, 0, stream>>>(gsum, pos, Wm1, bm1, Wm2, bm2, out);
}

// Round 15
// 133.376 us; speedup vs baseline: 1.9102x; 1.0564x over previous
//
#include <hip/hip_runtime.h>
#include <math.h>

#define NN 50000
#define NE 600000
#define HID 128
#define NG 64
#define CAP 48    // bucket capacity: Poisson(12) max-degree ~28; P(overflow)<1e-15
#define ASTRH 136 // LDS A-tile row stride in halves (272B): frag reads <=2-way
#define NBIN 196  // coarse bins: dst>>8, ceil(50000/256)
#define CHUNK 2344 // edges per hist/scatter block: ceil(600000/256)
#define TR 64     // MLP tile rows (R15: 128->64 for 2x grid, latency hiding)

using half8v = __attribute__((ext_vector_type(8))) _Float16;
using half2v = __attribute__((ext_vector_type(2))) _Float16;
using f32x4  = __attribute__((ext_vector_type(4))) float;

__device__ __forceinline__ float unpack_w(unsigned p) {
  return (float)__builtin_bit_cast(_Float16, (unsigned short)(p & 0xffffu));
}

// ---- Fused prep: pos | zero gsum | weight cast | per-block bin histogram ----
__global__ void k_prep(const int* __restrict__ batch, float* __restrict__ gsum,
                       int* __restrict__ pos,
                       const float* __restrict__ W1a, const float* __restrict__ W1b,
                       const float* __restrict__ W2a, const float* __restrict__ W2b,
                       _Float16* __restrict__ whi,
                       const int* __restrict__ dst, int* __restrict__ hist) {
  __shared__ int lh[NBIN];
  int b = blockIdx.x, t = threadIdx.x;
  if (b < 196) {
    int i = b * 256 + t;
    if (i < NN) {
      int bb = batch[i];
      if (i == 0) {
        for (int g = 0; g <= bb; ++g) pos[g] = 0;
      } else {
        int bp = batch[i - 1];
        for (int g = bp + 1; g <= bb; ++g) pos[g] = i;
      }
      if (i == NN - 1) {
        for (int g = bb + 1; g <= NG; ++g) pos[g] = NN;
      }
    }
  } else if (b < 204) {
    int i = (b - 196) * 256 + t;
    if (i < 2048) reinterpret_cast<float4*>(gsum)[i] = make_float4(0.f, 0.f, 0.f, 0.f);
  } else if (b < 236) {
    int tid = (b - 204) * 256 + t;  // 0..8191
    int m = tid >> 11;
    const float* W = (m == 0) ? W1a : (m == 1) ? W1b : (m == 2) ? W2a : W2b;
    int rem = tid & 2047;
    int kt = rem >> 9;
    int fj = (rem >> 6) & 7;
    int l = rem & 63;
    int col = fj * 16 + (l & 15);
    int kbase = kt * 32 + (l >> 4) * 8;
    size_t obase = (size_t)m * 16384 + (size_t)(((kt * 8 + fj) * 64 + l)) * 8;
#pragma unroll
    for (int j = 0; j < 8; ++j) {
      whi[obase + j] = (_Float16)W[(size_t)(kbase + j) * HID + col];
    }
  } else {
    int hb = b - 236;  // 0..255
    if (t < NBIN) lh[t] = 0;
    __syncthreads();
    int lo = hb * CHUNK, hi = min(lo + CHUNK, NE);
    for (int e = lo + t; e < hi; e += 256) atomicAdd(&lh[dst[e] >> 8], 1);
    __syncthreads();
    if (t < NBIN) hist[t * 256 + hb] = lh[t];
  }
}

// ---- Scatter: partition edges by bin (dst>>8). ZERO global atomics. ----
__global__ void k_scatter(const int* __restrict__ src, const int* __restrict__ dst,
                          const float* __restrict__ ew, const int* __restrict__ hist,
                          int* __restrict__ gbinbase, int2* __restrict__ part) {
  __shared__ int ps[256];
  __shared__ int cur[NBIN];
  int b = blockIdx.x, t = threadIdx.x;
  int sum0 = 0, T = 0;
  if (t < NBIN) {
    const int* row = &hist[t * 256];
#pragma unroll 4
    for (int i = 0; i < 256; ++i) {
      int v = row[i];
      T += v;
      sum0 += (i < b) ? v : 0;
    }
  }
  ps[t] = T;
  __syncthreads();
  for (int d = 1; d < 256; d <<= 1) {
    int u = (t >= d) ? ps[t - d] : 0;
    __syncthreads();
    ps[t] += u;
    __syncthreads();
  }
  if (t < NBIN) {
    int ebase = ps[t] - T;
    cur[t] = ebase + sum0;
    if (b == 0) gbinbase[t] = ebase;
  }
  if (b == 0 && t == 0) gbinbase[NBIN] = NE;
  __syncthreads();
  int lo = b * CHUNK, hi = min(lo + CHUNK, NE);
  for (int e = lo + t; e < hi; e += 256) {
    int d0 = dst[e];
    int p = atomicAdd(&cur[d0 >> 8], 1);  // LDS atomic
    _Float16 w = (_Float16)ew[e];
    unsigned wb = (unsigned)__builtin_bit_cast(unsigned short, w);
    part[p] = make_int2(src[e], ((d0 & 255) << 16) | (int)wb);
  }
}

// ---- Binfill: bin j's contiguous edges -> per-dst bucket slots (LDS cursors).
__global__ void k_binfill(const int2* __restrict__ part, const int* __restrict__ gbinbase,
                          unsigned* __restrict__ bkt, int* __restrict__ deg) {
  __shared__ int cur[256];
  int j = blockIdx.x, t = threadIdx.x;
  cur[t] = 0;
  __syncthreads();
  int lo = gbinbase[j], hi = gbinbase[j + 1];
  for (int e = lo + t; e < hi; e += 256) {
    int2 q = part[e];
    int dl = q.y >> 16;
    int p = atomicAdd(&cur[dl], 1);  // LDS atomic
    if (p < CAP)
      bkt[(size_t)((j << 8) + dl) * CAP + p] =
          ((unsigned)q.x << 16) | ((unsigned)q.y & 0xffffu);
  }
  __syncthreads();
  int node = (j << 8) + t;
  if (node < NN) deg[node] = cur[t];
}

// ---------------- Layer 1 aggregation (rank-1: scalars only), f16 out ----------
__global__ void k_layer1(const float* __restrict__ nw, const unsigned* __restrict__ bkt,
                         const int* __restrict__ deg,
                         const float* __restrict__ Wn, const float* __restrict__ bn,
                         const float* __restrict__ We, const float* __restrict__ be,
                         _Float16* __restrict__ h) {
  int wave = threadIdx.x >> 6;
  int lane = threadIdx.x & 63;
  int node = blockIdx.x * 4 + wave;
  if (node >= NN) return;
  int c = lane * 2;
  float wn0 = Wn[c], wn1 = Wn[c + 1];
  float we0 = We[c], we1 = We[c + 1];
  float bn0 = bn[c], bn1 = bn[c + 1];
  float cb0 = bn0 + be[c], cb1 = bn1 + be[c + 1];
  float ai = nw[node];
  float acc0 = fmaf(ai, wn0, bn0);
  float acc1 = fmaf(ai, wn1, bn1);
  int k0 = node * CAP;
  int cnt = min(deg[node], CAP);
  int k = 0;
  for (; k + 4 <= cnt; k += 4) {
    uint4 q = *reinterpret_cast<const uint4*>(&bkt[k0 + k]);
    float a0 = nw[q.x >> 16], a1 = nw[q.y >> 16];
    float a2 = nw[q.z >> 16], a3 = nw[q.w >> 16];
    float e0 = unpack_w(q.x), e1 = unpack_w(q.y);
    float e2 = unpack_w(q.z), e3 = unpack_w(q.w);
    acc0 += fmaxf(fmaf(a0, wn0, fmaf(e0, we0, cb0)), 0.f);
    acc1 += fmaxf(fmaf(a0, wn1, fmaf(e0, we1, cb1)), 0.f);
    acc0 += fmaxf(fmaf(a1, wn0, fmaf(e1, we0, cb0)), 0.f);
    acc1 += fmaxf(fmaf(a1, wn1, fmaf(e1, we1, cb1)), 0.f);
    acc0 += fmaxf(fmaf(a2, wn0, fmaf(e2, we0, cb0)), 0.f);
    acc1 += fmaxf(fmaf(a2, wn1, fmaf(e2, we1, cb1)), 0.f);
    acc0 += fmaxf(fmaf(a3, wn0, fmaf(e3, we0, cb0)), 0.f);
    acc1 += fmaxf(fmaf(a3, wn1, fmaf(e3, we1, cb1)), 0.f);
  }
  for (; k < cnt; ++k) {
    unsigned p = bkt[k0 + k];
    float a = nw[p >> 16];
    float b = unpack_w(p);
    acc0 += fmaxf(fmaf(a, wn0, fmaf(b, we0, cb0)), 0.f);
    acc1 += fmaxf(fmaf(a, wn1, fmaf(b, we1, cb1)), 0.f);
  }
  half2v o; o[0] = (_Float16)acc0; o[1] = (_Float16)acc1;
  *reinterpret_cast<half2v*>(&h[(size_t)node * HID + c]) = o;
}

// ---------------- Layer 2 aggregation: f16 gathers, 8 in flight ----------------
__global__ void k_layer2(const _Float16* __restrict__ x1, const unsigned* __restrict__ bkt,
                         const int* __restrict__ deg,
                         const float* __restrict__ We, const float* __restrict__ be,
                         _Float16* __restrict__ h) {
  int wave = threadIdx.x >> 6;
  int lane = threadIdx.x & 63;
  int node = blockIdx.x * 4 + wave;
  if (node >= NN) return;
  int c = lane * 2;
  float we0 = We[c], we1 = We[c + 1];
  float b0 = be[c], b1 = be[c + 1];
  half2v x = *reinterpret_cast<const half2v*>(&x1[(size_t)node * HID + c]);
  float acc0 = (float)x[0], acc1 = (float)x[1];
  int k0 = node * CAP;
  int cnt = min(deg[node], CAP);
  int k = 0;
  for (; k + 8 <= cnt; k += 8) {  // 8 independent row gathers in flight
    uint4 qa = *reinterpret_cast<const uint4*>(&bkt[k0 + k]);
    uint4 qb = *reinterpret_cast<const uint4*>(&bkt[k0 + k + 4]);
    half2v r0 = *reinterpret_cast<const half2v*>(&x1[(size_t)(qa.x >> 16) * HID + c]);
    half2v r1 = *reinterpret_cast<const half2v*>(&x1[(size_t)(qa.y >> 16) * HID + c]);
    half2v r2 = *reinterpret_cast<const half2v*>(&x1[(size_t)(qa.z >> 16) * HID + c]);
    half2v r3 = *reinterpret_cast<const half2v*>(&x1[(size_t)(qa.w >> 16) * HID + c]);
    half2v r4 = *reinterpret_cast<const half2v*>(&x1[(size_t)(qb.x >> 16) * HID + c]);
    half2v r5 = *reinterpret_cast<const half2v*>(&x1[(size_t)(qb.y >> 16) * HID + c]);
    half2v r6 = *reinterpret_cast<const half2v*>(&x1[(size_t)(qb.z >> 16) * HID + c]);
    half2v r7 = *reinterpret_cast<const half2v*>(&x1[(size_t)(qb.w >> 16) * HID + c]);
    float e0 = unpack_w(qa.x), e1 = unpack_w(qa.y);
    float e2 = unpack_w(qa.z), e3 = unpack_w(qa.w);
    float e4 = unpack_w(qb.x), e5 = unpack_w(qb.y);
    float e6 = unpack_w(qb.z), e7 = unpack_w(qb.w);
    acc0 += fmaxf((float)r0[0] + fmaf(e0, we0, b0), 0.f);
    acc1 += fmaxf((float)r0[1] + fmaf(e0, we1, b1), 0.f);
    acc0 += fmaxf((float)r1[0] + fmaf(e1, we0, b0), 0.f);
    acc1 += fmaxf((float)r1[1] + fmaf(e1, we1, b1), 0.f);
    acc0 += fmaxf((float)r2[0] + fmaf(e2, we0, b0), 0.f);
    acc1 += fmaxf((float)r2[1] + fmaf(e2, we1, b1), 0.f);
    acc0 += fmaxf((float)r3[0] + fmaf(e3, we0, b0), 0.f);
    acc1 += fmaxf((float)r3[1] + fmaf(e3, we1, b1), 0.f);
    acc0 += fmaxf((float)r4[0] + fmaf(e4, we0, b0), 0.f);
    acc1 += fmaxf((float)r4[1] + fmaf(e4, we1, b1), 0.f);
    acc0 += fmaxf((float)r5[0] + fmaf(e5, we0, b0), 0.f);
    acc1 += fmaxf((float)r5[1] + fmaf(e5, we1, b1), 0.f);
    acc0 += fmaxf((float)r6[0] + fmaf(e6, we0, b0), 0.f);
    acc1 += fmaxf((float)r6[1] + fmaf(e6, we1, b1), 0.f);
    acc0 += fmaxf((float)r7[0] + fmaf(e7, we0, b0), 0.f);
    acc1 += fmaxf((float)r7[1] + fmaf(e7, we1, b1), 0.f);
  }
  for (; k + 4 <= cnt; k += 4) {
    uint4 q = *reinterpret_cast<const uint4*>(&bkt[k0 + k]);
    half2v r0 = *reinterpret_cast<const half2v*>(&x1[(size_t)(q.x >> 16) * HID + c]);
    half2v r1 = *reinterpret_cast<const half2v*>(&x1[(size_t)(q.y >> 16) * HID + c]);
    half2v r2 = *reinterpret_cast<const half2v*>(&x1[(size_t)(q.z >> 16) * HID + c]);
    half2v r3 = *reinterpret_cast<const half2v*>(&x1[(size_t)(q.w >> 16) * HID + c]);
    float e0 = unpack_w(q.x), e1 = unpack_w(q.y);
    float e2 = unpack_w(q.z), e3 = unpack_w(q.w);
    acc0 += fmaxf((float)r0[0] + fmaf(e0, we0, b0), 0.f);
    acc1 += fmaxf((float)r0[1] + fmaf(e0, we1, b1), 0.f);
    acc0 += fmaxf((float)r1[0] + fmaf(e1, we0, b0), 0.f);
    acc1 += fmaxf((float)r1[1] + fmaf(e1, we1, b1), 0.f);
    acc0 += fmaxf((float)r2[0] + fmaf(e2, we0, b0), 0.f);
    acc1 += fmaxf((float)r2[1] + fmaf(e2, we1, b1), 0.f);
    acc0 += fmaxf((float)r3[0] + fmaf(e3, we0, b0), 0.f);
    acc1 += fmaxf((float)r3[1] + fmaf(e3, we1, b1), 0.f);
  }
  for (; k < cnt; ++k) {
    unsigned p = bkt[k0 + k];
    float b = unpack_w(p);
    half2v xs = *reinterpret_cast<const half2v*>(&x1[(size_t)(p >> 16) * HID + c]);
    acc0 += fmaxf((float)xs[0] + fmaf(b, we0, b0), 0.f);
    acc1 += fmaxf((float)xs[1] + fmaf(b, we1, b1), 0.f);
  }
  half2v o; o[0] = (_Float16)acc0; o[1] = (_Float16)acc1;
  *reinterpret_cast<half2v*>(&h[(size_t)node * HID + c]) = o;
}

// ---------------- MFMA MLP pair: Y = relu(leaky(X@Wa+ba)@Wb+bb) ----------------
// R15: 64-row tiles -> 782 blocks (3.05/CU, was 1.53), LDS 17.7KB, up to 6
// blocks/CU resident -> ~4.5x the waves/SIMD to hide the W-fragment L2 latency
// (the kernel's bottleneck: 64 MFMAs ~ 320cy vs ~13k cy observed per wave).
// Wave owns 16 rows x 128 cols (1x8 fragments).
template <int POOL>
__global__ __launch_bounds__(256, 6) void k_mlp(
    const _Float16* __restrict__ X,
    const _Float16* __restrict__ Wah, const float* __restrict__ ba,
    const _Float16* __restrict__ Wbh, const float* __restrict__ bb,
    _Float16* __restrict__ Y,
    const int* __restrict__ batch, float* __restrict__ gsum) {
  extern __shared__ char smem_raw[];
  _Float16* Ah = (_Float16*)smem_raw;
  int* sB = (int*)(smem_raw + TR * ASTRH * 2);
  const int tid = threadIdx.x;
  const int l = tid & 63;
  const int wrow = (tid >> 6) * 16;
  const int rowBase = blockIdx.x * TR;

  if (POOL && tid < TR) sB[tid] = batch[min(rowBase + tid, NN - 1)];

  // ---- stage X(f16) -> Ah (16 lanes cover one 256B row; 4 rows/thread) ----
  {
    int rr = tid >> 4;         // 0..15
    int c0 = (tid & 15) * 8;   // 0..120
#pragma unroll
    for (int p = 0; p < 4; ++p) {
      int r = p * 16 + rr;
      int srcRow = min(rowBase + r, NN - 1);
      half8v v = *reinterpret_cast<const half8v*>(&X[(size_t)srcRow * HID + c0]);
      *reinterpret_cast<half8v*>(&Ah[r * ASTRH + c0]) = v;
    }
  }
  __syncthreads();

  const int arow0 = wrow + (l & 15);
  const int kgrp = (l >> 4) * 8;
  const int lcol = l & 15;

  // ---- GEMM1: acc = X @ Wa ----
  f32x4 acc[8];
#pragma unroll
  for (int j = 0; j < 8; ++j) acc[j] = f32x4{0.f, 0.f, 0.f, 0.f};

#pragma unroll
  for (int ks = 0; ks < 4; ++ks) {
    half8v a0 = *reinterpret_cast<const half8v*>(&Ah[arow0 * ASTRH + ks * 32 + kgrp]);
    const _Float16* wbh = &Wah[(size_t)((ks * 8) * 64 + l) * 8];
#pragma unroll
    for (int fj = 0; fj < 8; ++fj) {
      half8v bh = *reinterpret_cast<const half8v*>(wbh + fj * 512);
      acc[fj] = __builtin_amdgcn_mfma_f32_16x16x32_f16(a0, bh, acc[fj], 0, 0, 0);
    }
  }

  // ---- t = leaky(acc + ba) -> back into Ah (wave-local rows; no barrier) ----
  {
    float bal[8];
#pragma unroll
    for (int fj = 0; fj < 8; ++fj) bal[fj] = ba[fj * 16 + lcol];
    int rbase = wrow + ((l >> 4) << 2);
#pragma unroll
    for (int fj = 0; fj < 8; ++fj) {
#pragma unroll
      for (int r = 0; r < 4; ++r) {
        float v = acc[fj][r] + bal[fj];
        v = (v > 0.f) ? v : 0.01f * v;
        Ah[(rbase + r) * ASTRH + fj * 16 + lcol] = (_Float16)v;
      }
    }
  }

  // ---- GEMM2: acc2 = t @ Wb (t is wave-local in Ah) ----
  f32x4 acc2[8];
#pragma unroll
  for (int j = 0; j < 8; ++j) acc2[j] = f32x4{0.f, 0.f, 0.f, 0.f};

#pragma unroll
  for (int ks = 0; ks < 4; ++ks) {
    half8v a0 = *reinterpret_cast<const half8v*>(&Ah[arow0 * ASTRH + ks * 32 + kgrp]);
    const _Float16* wbh = &Wbh[(size_t)((ks * 8) * 64 + l) * 8];
#pragma unroll
    for (int fj = 0; fj < 8; ++fj) {
      half8v bh = *reinterpret_cast<const half8v*>(wbh + fj * 512);
      acc2[fj] = __builtin_amdgcn_mfma_f32_16x16x32_f16(a0, bh, acc2[fj], 0, 0, 0);
    }
  }

  // ---- epilogue: relu(acc2 + bb) ----
  float bbl[8];
#pragma unroll
  for (int fj = 0; fj < 8; ++fj) bbl[fj] = bb[fj * 16 + lcol];
  const int rbase = wrow + ((l >> 4) << 2);

  if (!POOL) {
#pragma unroll
    for (int fj = 0; fj < 8; ++fj) {
#pragma unroll
      for (int r = 0; r < 4; ++r) {
        int row = rowBase + rbase + r;
        if (row < NN)
          Y[(size_t)row * HID + fj * 16 + lcol] =
              (_Float16)fmaxf(acc2[fj][r] + bbl[fj], 0.f);
      }
    }
  } else {
    __syncthreads();  // all GEMM2 t-reads done; reuse LDS as f16 sPh[TR][132]
    _Float16* sPh = (_Float16*)smem_raw;
#pragma unroll
    for (int fj = 0; fj < 8; ++fj) {
#pragma unroll
      for (int r = 0; r < 4; ++r) {
        bool ok = (rowBase + rbase + r) < NN;
        float z = fmaxf(acc2[fj][r] + bbl[fj], 0.f);
        sPh[(rbase + r) * 132 + fj * 16 + lcol] = (_Float16)(ok ? z : 0.f);
      }
    }
    __syncthreads();
    if (tid < HID) {  // batch sorted: run-length reduce, few atomics/block
      int cur = sB[0];
      float run = 0.f;
      for (int r = 0; r < TR; ++r) {
        int g = sB[r];
        if (g != cur) {
          atomicAdd(&gsum[cur * HID + tid], run);
          run = 0.f; cur = g;
        }
        run += (float)sPh[r * 132 + tid];
      }
      atomicAdd(&gsum[cur * HID + tid], run);
    }
  }
}

// ---------------- Final: pooled MLP -> sigmoid ----------------
__global__ void k_final(const float* __restrict__ gsum, const int* __restrict__ pos,
                        const float* __restrict__ Wm1, const float* __restrict__ bm1,
                        const float* __restrict__ Wm2, const float* __restrict__ bm2,
                        float* __restrict__ out) {
  __shared__ float sp[HID];
  __shared__ float red[HID];
  int g = blockIdx.x;
  int k = threadIdx.x;  // 128 threads
  float c = fmaxf((float)(pos[g + 1] - pos[g]), 1.f);
  sp[k] = gsum[g * HID + k] / c;
  __syncthreads();
  float dot = 0.f;
  for (int j = 0; j < HID; ++j) dot = fmaf(sp[j], Wm1[j * HID + k], dot);
  float z = dot + bm1[k];
  z = (z > 0.f) ? z : 0.01f * z;
  red[k] = z * Wm2[k];
  __syncthreads();
  for (int s = 64; s > 0; s >>= 1) {
    if (k < s) red[k] += red[k + s];
    __syncthreads();
  }
  if (k == 0) out[g] = 1.f / (1.f + expf(-(red[0] + bm2[0])));
}

extern "C" void kernel_launch(void* const* d_in, const int* in_sizes, int n_in,
                              void* d_out, int out_size, void* d_ws, size_t ws_size,
                              hipStream_t stream) {
  const float* nw = (const float*)d_in[0];
  const float* ew = (const float*)d_in[1];
  const int* ei = (const int*)d_in[2];
  const int* src = ei;
  const int* dst = ei + NE;
  const int* batch = (const int*)d_in[3];
  const float* Wn = (const float*)d_in[4];
  const float* bn = (const float*)d_in[5];
  const float* We = (const float*)d_in[6];
  const float* be = (const float*)d_in[7];
  const float* W1a = (const float*)d_in[8];
  const float* b1a = (const float*)d_in[9];
  const float* W1b = (const float*)d_in[10];
  const float* b1b = (const float*)d_in[11];
  const float* W2a = (const float*)d_in[12];
  const float* b2a = (const float*)d_in[13];
  const float* W2b = (const float*)d_in[14];
  const float* b2b = (const float*)d_in[15];
  const float* Wm1 = (const float*)d_in[16];
  const float* bm1 = (const float*)d_in[17];
  const float* Wm2 = (const float*)d_in[18];
  const float* bm2 = (const float*)d_in[19];
  float* out = (float*)d_out;

  char* ws = (char*)d_ws;
  size_t o = 0;
  auto alloc = [&](size_t b) {
    size_t p = o;
    o += (b + 255) & ~(size_t)255;
    return p;
  };
  size_t deg_o = alloc(NN * 4);                 // written by binfill (no pre-zero)
  size_t gsum_o = alloc((size_t)NG * HID * 4);
  size_t pos_o = alloc((NG + 1) * 4);
  size_t hist_o = alloc((size_t)NBIN * 256 * 4);
  size_t gbb_o = alloc((NBIN + 1) * 4);
  size_t part_o = alloc((size_t)NE * 8);        // bin-partitioned edges
  size_t bkt_o = alloc((size_t)NN * CAP * 4);   // packed-u32 bucketed CSR
  size_t h1_o = alloc((size_t)NN * HID * 2);
  size_t x1_o = alloc((size_t)NN * HID * 2);
  size_t h2_o = alloc((size_t)NN * HID * 2);
  size_t whi_o = alloc((size_t)4 * 16384 * 2);  // f16, 4 matrices frag-linear

  int* deg = (int*)(ws + deg_o);
  float* gsum = (float*)(ws + gsum_o);
  int* pos = (int*)(ws + pos_o);
  int* hist = (int*)(ws + hist_o);
  int* gbinbase = (int*)(ws + gbb_o);
  int2* part = (int2*)(ws + part_o);
  unsigned* bkt = (unsigned*)(ws + bkt_o);
  _Float16* h1 = (_Float16*)(ws + h1_o);
  _Float16* x1h = (_Float16*)(ws + x1_o);
  _Float16* h2 = (_Float16*)(ws + h2_o);
  _Float16* whi = (_Float16*)(ws + whi_o);

  // 8 dispatches, zero global atomics in the CSR build
  k_prep<<<492, 256, 0, stream>>>(batch, gsum, pos, W1a, W1b, W2a, W2b, whi,
                                  dst, hist);
  k_scatter<<<256, 256, 0, stream>>>(src, dst, ew, hist, gbinbase, part);
  k_binfill<<<NBIN, 256, 0, stream>>>(part, gbinbase, bkt, deg);

  k_layer1<<<NN / 4, 256, 0, stream>>>(nw, bkt, deg, Wn, bn, We, be, h1);

  size_t smem = (size_t)TR * ASTRH * 2 + TR * 4;  // 17,664 B -> up to 6 blocks/CU
  const int mlpBlocks = (NN + TR - 1) / TR;  // 782
  k_mlp<0><<<mlpBlocks, 256, smem, stream>>>(h1, whi, b1a, whi + 16384, b1b,
                                             x1h, nullptr, nullptr);

  k_layer2<<<NN / 4, 256, 0, stream>>>(x1h, bkt, deg, We, be, h2);

  k_mlp<1><<<mlpBlocks, 256, smem, stream>>>(h2, whi + 2 * 16384, b2a,
                                             whi + 3 * 16384, b2b,
                                             nullptr, batch, gsum);

  k_final<<<NG, HID, 0, stream>>>(gsum, pos, Wm1, bm1, Wm2, bm2, out);
}

// Round 16
// 131.796 us; speedup vs baseline: 1.9331x; 1.0120x over previous
//
#include <hip/hip_runtime.h>
#include <math.h>

#define NN 50000
#define NE 600000
#define HID 128
#define NG 64
#define CAP 48    // bucket capacity: Poisson(12) max-degree ~28; P(overflow)<1e-15
#define ASTRH 136 // LDS A-tile row stride in halves (272B): frag reads <=2-way
#define NBIN 196  // coarse bins: dst>>8, ceil(50000/256)
#define CHUNK 2344 // edges per hist/scatter block: ceil(600000/256)
#define TR 64     // MLP tile rows

using half8v = __attribute__((ext_vector_type(8))) _Float16;
using half4v = __attribute__((ext_vector_type(4))) _Float16;
using half2v = __attribute__((ext_vector_type(2))) _Float16;
using f32x4  = __attribute__((ext_vector_type(4))) float;

__device__ __forceinline__ float unpack_w(unsigned p) {
  return (float)__builtin_bit_cast(_Float16, (unsigned short)(p & 0xffffu));
}

// ---- Fused prep: pos | zero gsum | weight cast | per-block bin histogram ----
__global__ void k_prep(const int* __restrict__ batch, float* __restrict__ gsum,
                       int* __restrict__ pos,
                       const float* __restrict__ W1a, const float* __restrict__ W1b,
                       const float* __restrict__ W2a, const float* __restrict__ W2b,
                       _Float16* __restrict__ whi,
                       const int* __restrict__ dst, int* __restrict__ hist) {
  __shared__ int lh[NBIN];
  int b = blockIdx.x, t = threadIdx.x;
  if (b < 196) {
    int i = b * 256 + t;
    if (i < NN) {
      int bb = batch[i];
      if (i == 0) {
        for (int g = 0; g <= bb; ++g) pos[g] = 0;
      } else {
        int bp = batch[i - 1];
        for (int g = bp + 1; g <= bb; ++g) pos[g] = i;
      }
      if (i == NN - 1) {
        for (int g = bb + 1; g <= NG; ++g) pos[g] = NN;
      }
    }
  } else if (b < 204) {
    int i = (b - 196) * 256 + t;
    if (i < 2048) reinterpret_cast<float4*>(gsum)[i] = make_float4(0.f, 0.f, 0.f, 0.f);
  } else if (b < 236) {
    int tid = (b - 204) * 256 + t;  // 0..8191
    int m = tid >> 11;
    const float* W = (m == 0) ? W1a : (m == 1) ? W1b : (m == 2) ? W2a : W2b;
    int rem = tid & 2047;
    int kt = rem >> 9;
    int fj = (rem >> 6) & 7;
    int l = rem & 63;
    int col = fj * 16 + (l & 15);
    int kbase = kt * 32 + (l >> 4) * 8;
    size_t obase = (size_t)m * 16384 + (size_t)(((kt * 8 + fj) * 64 + l)) * 8;
#pragma unroll
    for (int j = 0; j < 8; ++j) {
      whi[obase + j] = (_Float16)W[(size_t)(kbase + j) * HID + col];
    }
  } else {
    int hb = b - 236;  // 0..255
    if (t < NBIN) lh[t] = 0;
    __syncthreads();
    int lo = hb * CHUNK, hi = min(lo + CHUNK, NE);
    for (int e = lo + t; e < hi; e += 256) atomicAdd(&lh[dst[e] >> 8], 1);
    __syncthreads();
    if (t < NBIN) hist[t * 256 + hb] = lh[t];
  }
}

// ---- Scatter: partition edges by bin (dst>>8). ZERO global atomics. ----
__global__ void k_scatter(const int* __restrict__ src, const int* __restrict__ dst,
                          const float* __restrict__ ew, const int* __restrict__ hist,
                          int* __restrict__ gbinbase, int2* __restrict__ part) {
  __shared__ int ps[256];
  __shared__ int cur[NBIN];
  int b = blockIdx.x, t = threadIdx.x;
  int sum0 = 0, T = 0;
  if (t < NBIN) {
    const int* row = &hist[t * 256];
#pragma unroll 4
    for (int i = 0; i < 256; ++i) {
      int v = row[i];
      T += v;
      sum0 += (i < b) ? v : 0;
    }
  }
  ps[t] = T;
  __syncthreads();
  for (int d = 1; d < 256; d <<= 1) {
    int u = (t >= d) ? ps[t - d] : 0;
    __syncthreads();
    ps[t] += u;
    __syncthreads();
  }
  if (t < NBIN) {
    int ebase = ps[t] - T;
    cur[t] = ebase + sum0;
    if (b == 0) gbinbase[t] = ebase;
  }
  if (b == 0 && t == 0) gbinbase[NBIN] = NE;
  __syncthreads();
  int lo = b * CHUNK, hi = min(lo + CHUNK, NE);
  for (int e = lo + t; e < hi; e += 256) {
    int d0 = dst[e];
    int p = atomicAdd(&cur[d0 >> 8], 1);  // LDS atomic
    _Float16 w = (_Float16)ew[e];
    unsigned wb = (unsigned)__builtin_bit_cast(unsigned short, w);
    part[p] = make_int2(src[e], ((d0 & 255) << 16) | (int)wb);
  }
}

// ---- Binfill: bin j's contiguous edges -> per-dst bucket slots (LDS cursors).
__global__ void k_binfill(const int2* __restrict__ part, const int* __restrict__ gbinbase,
                          unsigned* __restrict__ bkt, int* __restrict__ deg) {
  __shared__ int cur[256];
  int j = blockIdx.x, t = threadIdx.x;
  cur[t] = 0;
  __syncthreads();
  int lo = gbinbase[j], hi = gbinbase[j + 1];
  for (int e = lo + t; e < hi; e += 256) {
    int2 q = part[e];
    int dl = q.y >> 16;
    int p = atomicAdd(&cur[dl], 1);  // LDS atomic
    if (p < CAP)
      bkt[(size_t)((j << 8) + dl) * CAP + p] =
          ((unsigned)q.x << 16) | ((unsigned)q.y & 0xffffu);
  }
  __syncthreads();
  int node = (j << 8) + t;
  if (node < NN) deg[node] = cur[t];
}

// ---------------- Layer 1 aggregation (rank-1: scalars only), f16 out ----------
__global__ void k_layer1(const float* __restrict__ nw, const unsigned* __restrict__ bkt,
                         const int* __restrict__ deg,
                         const float* __restrict__ Wn, const float* __restrict__ bn,
                         const float* __restrict__ We, const float* __restrict__ be,
                         _Float16* __restrict__ h) {
  int wave = threadIdx.x >> 6;
  int lane = threadIdx.x & 63;
  int node = blockIdx.x * 4 + wave;
  if (node >= NN) return;
  int c = lane * 2;
  float wn0 = Wn[c], wn1 = Wn[c + 1];
  float we0 = We[c], we1 = We[c + 1];
  float bn0 = bn[c], bn1 = bn[c + 1];
  float cb0 = bn0 + be[c], cb1 = bn1 + be[c + 1];
  float ai = nw[node];
  float acc0 = fmaf(ai, wn0, bn0);
  float acc1 = fmaf(ai, wn1, bn1);
  int k0 = node * CAP;
  int cnt = min(deg[node], CAP);
  int k = 0;
  for (; k + 4 <= cnt; k += 4) {
    uint4 q = *reinterpret_cast<const uint4*>(&bkt[k0 + k]);
    float a0 = nw[q.x >> 16], a1 = nw[q.y >> 16];
    float a2 = nw[q.z >> 16], a3 = nw[q.w >> 16];
    float e0 = unpack_w(q.x), e1 = unpack_w(q.y);
    float e2 = unpack_w(q.z), e3 = unpack_w(q.w);
    acc0 += fmaxf(fmaf(a0, wn0, fmaf(e0, we0, cb0)), 0.f);
    acc1 += fmaxf(fmaf(a0, wn1, fmaf(e0, we1, cb1)), 0.f);
    acc0 += fmaxf(fmaf(a1, wn0, fmaf(e1, we0, cb0)), 0.f);
    acc1 += fmaxf(fmaf(a1, wn1, fmaf(e1, we1, cb1)), 0.f);
    acc0 += fmaxf(fmaf(a2, wn0, fmaf(e2, we0, cb0)), 0.f);
    acc1 += fmaxf(fmaf(a2, wn1, fmaf(e2, we1, cb1)), 0.f);
    acc0 += fmaxf(fmaf(a3, wn0, fmaf(e3, we0, cb0)), 0.f);
    acc1 += fmaxf(fmaf(a3, wn1, fmaf(e3, we1, cb1)), 0.f);
  }
  for (; k < cnt; ++k) {
    unsigned p = bkt[k0 + k];
    float a = nw[p >> 16];
    float b = unpack_w(p);
    acc0 += fmaxf(fmaf(a, wn0, fmaf(b, we0, cb0)), 0.f);
    acc1 += fmaxf(fmaf(a, wn1, fmaf(b, we1, cb1)), 0.f);
  }
  half2v o; o[0] = (_Float16)acc0; o[1] = (_Float16)acc1;
  *reinterpret_cast<half2v*>(&h[(size_t)node * HID + c]) = o;
}

// ---------------- Layer 2 aggregation: node-paired gathers ----------------
// R16: each wave serves TWO nodes (half-wave per node), lane covers 4 channels
// (8B/lane). Every gather instruction fetches two 256B rows (one per half) ->
// 2x bytes-in-flight per issued load vs the 1-node/wave version. Loop bound =
// wave-max degree via shfl_xor; per-edge predication (clamped src for the
// inactive tail; bkt reads stay < CAP, in bounds).
__global__ void k_layer2(const _Float16* __restrict__ x1, const unsigned* __restrict__ bkt,
                         const int* __restrict__ deg,
                         const float* __restrict__ We, const float* __restrict__ be,
                         _Float16* __restrict__ h) {
  int wave = threadIdx.x >> 6;
  int l = threadIdx.x & 63;
  int half = l >> 5;
  int lane32 = l & 31;
  int node = blockIdx.x * 8 + wave * 2 + half;  // grid 6250 * 8 = NN exactly
  int c = lane32 * 4;
  float4 w4 = *reinterpret_cast<const float4*>(&We[c]);
  float4 b4 = *reinterpret_cast<const float4*>(&be[c]);
  half4v xs = *reinterpret_cast<const half4v*>(&x1[(size_t)node * HID + c]);
  float acc0 = (float)xs[0], acc1 = (float)xs[1];
  float acc2 = (float)xs[2], acc3 = (float)xs[3];
  int cnt = min(deg[node], CAP);
  int cntO = __shfl_xor(cnt, 32);
  int kmax = max(cnt, cntO);  // wave-uniform
  int k0 = node * CAP;

  for (int k = 0; k < kmax; k += 8) {
    uint4 qa = *reinterpret_cast<const uint4*>(&bkt[k0 + k]);      // per-half bcast
    uint4 qb = *reinterpret_cast<const uint4*>(&bkt[k0 + k + 4]);
    unsigned qs[8] = {qa.x, qa.y, qa.z, qa.w, qb.x, qb.y, qb.z, qb.w};
    half4v r[8];
#pragma unroll
    for (int i = 0; i < 8; ++i) {  // issue all 8 gathers (2 rows each) first
      int s = min((int)(qs[i] >> 16), NN - 1);
      r[i] = *reinterpret_cast<const half4v*>(&x1[(size_t)s * HID + c]);
    }
#pragma unroll
    for (int i = 0; i < 8; ++i) {
      bool v = (k + i) < cnt;
      float e = unpack_w(qs[i]);
      float m0 = fmaxf((float)r[i][0] + fmaf(e, w4.x, b4.x), 0.f);
      float m1 = fmaxf((float)r[i][1] + fmaf(e, w4.y, b4.y), 0.f);
      float m2 = fmaxf((float)r[i][2] + fmaf(e, w4.z, b4.z), 0.f);
      float m3 = fmaxf((float)r[i][3] + fmaf(e, w4.w, b4.w), 0.f);
      acc0 += v ? m0 : 0.f;
      acc1 += v ? m1 : 0.f;
      acc2 += v ? m2 : 0.f;
      acc3 += v ? m3 : 0.f;
    }
  }
  half4v o;
  o[0] = (_Float16)acc0; o[1] = (_Float16)acc1;
  o[2] = (_Float16)acc2; o[3] = (_Float16)acc3;
  *reinterpret_cast<half4v*>(&h[(size_t)node * HID + c]) = o;
}

// ---------------- MFMA MLP pair: Y = relu(leaky(X@Wa+ba)@Wb+bb) ----------------
// 64-row tiles -> 782 blocks (3.05/CU), LDS 17.7KB. Wave owns 16 rows x 128 cols.
template <int POOL>
__global__ __launch_bounds__(256, 6) void k_mlp(
    const _Float16* __restrict__ X,
    const _Float16* __restrict__ Wah, const float* __restrict__ ba,
    const _Float16* __restrict__ Wbh, const float* __restrict__ bb,
    _Float16* __restrict__ Y,
    const int* __restrict__ batch, float* __restrict__ gsum) {
  extern __shared__ char smem_raw[];
  _Float16* Ah = (_Float16*)smem_raw;
  int* sB = (int*)(smem_raw + TR * ASTRH * 2);
  const int tid = threadIdx.x;
  const int l = tid & 63;
  const int wrow = (tid >> 6) * 16;
  const int rowBase = blockIdx.x * TR;

  if (POOL && tid < TR) sB[tid] = batch[min(rowBase + tid, NN - 1)];

  {
    int rr = tid >> 4;         // 0..15
    int c0 = (tid & 15) * 8;   // 0..120
#pragma unroll
    for (int p = 0; p < 4; ++p) {
      int r = p * 16 + rr;
      int srcRow = min(rowBase + r, NN - 1);
      half8v v = *reinterpret_cast<const half8v*>(&X[(size_t)srcRow * HID + c0]);
      *reinterpret_cast<half8v*>(&Ah[r * ASTRH + c0]) = v;
    }
  }
  __syncthreads();

  const int arow0 = wrow + (l & 15);
  const int kgrp = (l >> 4) * 8;
  const int lcol = l & 15;

  f32x4 acc[8];
#pragma unroll
  for (int j = 0; j < 8; ++j) acc[j] = f32x4{0.f, 0.f, 0.f, 0.f};

#pragma unroll
  for (int ks = 0; ks < 4; ++ks) {
    half8v a0 = *reinterpret_cast<const half8v*>(&Ah[arow0 * ASTRH + ks * 32 + kgrp]);
    const _Float16* wbh = &Wah[(size_t)((ks * 8) * 64 + l) * 8];
#pragma unroll
    for (int fj = 0; fj < 8; ++fj) {
      half8v bh = *reinterpret_cast<const half8v*>(wbh + fj * 512);
      acc[fj] = __builtin_amdgcn_mfma_f32_16x16x32_f16(a0, bh, acc[fj], 0, 0, 0);
    }
  }

  {
    float bal[8];
#pragma unroll
    for (int fj = 0; fj < 8; ++fj) bal[fj] = ba[fj * 16 + lcol];
    int rbase = wrow + ((l >> 4) << 2);
#pragma unroll
    for (int fj = 0; fj < 8; ++fj) {
#pragma unroll
      for (int r = 0; r < 4; ++r) {
        float v = acc[fj][r] + bal[fj];
        v = (v > 0.f) ? v : 0.01f * v;
        Ah[(rbase + r) * ASTRH + fj * 16 + lcol] = (_Float16)v;
      }
    }
  }

  f32x4 acc2[8];
#pragma unroll
  for (int j = 0; j < 8; ++j) acc2[j] = f32x4{0.f, 0.f, 0.f, 0.f};

#pragma unroll
  for (int ks = 0; ks < 4; ++ks) {
    half8v a0 = *reinterpret_cast<const half8v*>(&Ah[arow0 * ASTRH + ks * 32 + kgrp]);
    const _Float16* wbh = &Wbh[(size_t)((ks * 8) * 64 + l) * 8];
#pragma unroll
    for (int fj = 0; fj < 8; ++fj) {
      half8v bh = *reinterpret_cast<const half8v*>(wbh + fj * 512);
      acc2[fj] = __builtin_amdgcn_mfma_f32_16x16x32_f16(a0, bh, acc2[fj], 0, 0, 0);
    }
  }

  float bbl[8];
#pragma unroll
  for (int fj = 0; fj < 8; ++fj) bbl[fj] = bb[fj * 16 + lcol];
  const int rbase = wrow + ((l >> 4) << 2);

  if (!POOL) {
#pragma unroll
    for (int fj = 0; fj < 8; ++fj) {
#pragma unroll
      for (int r = 0; r < 4; ++r) {
        int row = rowBase + rbase + r;
        if (row < NN)
          Y[(size_t)row * HID + fj * 16 + lcol] =
              (_Float16)fmaxf(acc2[fj][r] + bbl[fj], 0.f);
      }
    }
  } else {
    __syncthreads();
    _Float16* sPh = (_Float16*)smem_raw;
#pragma unroll
    for (int fj = 0; fj < 8; ++fj) {
#pragma unroll
      for (int r = 0; r < 4; ++r) {
        bool ok = (rowBase + rbase + r) < NN;
        float z = fmaxf(acc2[fj][r] + bbl[fj], 0.f);
        sPh[(rbase + r) * 132 + fj * 16 + lcol] = (_Float16)(ok ? z : 0.f);
      }
    }
    __syncthreads();
    if (tid < HID) {
      int cur = sB[0];
      float run = 0.f;
      for (int r = 0; r < TR; ++r) {
        int g = sB[r];
        if (g != cur) {
          atomicAdd(&gsum[cur * HID + tid], run);
          run = 0.f; cur = g;
        }
        run += (float)sPh[r * 132 + tid];
      }
      atomicAdd(&gsum[cur * HID + tid], run);
    }
  }
}

// ---------------- Final: pooled MLP -> sigmoid ----------------
__global__ void k_final(const float* __restrict__ gsum, const int* __restrict__ pos,
                        const float* __restrict__ Wm1, const float* __restrict__ bm1,
                        const float* __restrict__ Wm2, const float* __restrict__ bm2,
                        float* __restrict__ out) {
  __shared__ float sp[HID];
  __shared__ float red[HID];
  int g = blockIdx.x;
  int k = threadIdx.x;  // 128 threads
  float c = fmaxf((float)(pos[g + 1] - pos[g]), 1.f);
  sp[k] = gsum[g * HID + k] / c;
  __syncthreads();
  float dot = 0.f;
  for (int j = 0; j < HID; ++j) dot = fmaf(sp[j], Wm1[j * HID + k], dot);
  float z = dot + bm1[k];
  z = (z > 0.f) ? z : 0.01f * z;
  red[k] = z * Wm2[k];
  __syncthreads();
  for (int s = 64; s > 0; s >>= 1) {
    if (k < s) red[k] += red[k + s];
    __syncthreads();
  }
  if (k == 0) out[g] = 1.f / (1.f + expf(-(red[0] + bm2[0])));
}

extern "C" void kernel_launch(void* const* d_in, const int* in_sizes, int n_in,
                              void* d_out, int out_size, void* d_ws, size_t ws_size,
                              hipStream_t stream) {
  const float* nw = (const float*)d_in[0];
  const float* ew = (const float*)d_in[1];
  const int* ei = (const int*)d_in[2];
  const int* src = ei;
  const int* dst = ei + NE;
  const int* batch = (const int*)d_in[3];
  const float* Wn = (const float*)d_in[4];
  const float* bn = (const float*)d_in[5];
  const float* We = (const float*)d_in[6];
  const float* be = (const float*)d_in[7];
  const float* W1a = (const float*)d_in[8];
  const float* b1a = (const float*)d_in[9];
  const float* W1b = (const float*)d_in[10];
  const float* b1b = (const float*)d_in[11];
  const float* W2a = (const float*)d_in[12];
  const float* b2a = (const float*)d_in[13];
  const float* W2b = (const float*)d_in[14];
  const float* b2b = (const float*)d_in[15];
  const float* Wm1 = (const float*)d_in[16];
  const float* bm1 = (const float*)d_in[17];
  const float* Wm2 = (const float*)d_in[18];
  const float* bm2 = (const float*)d_in[19];
  float* out = (float*)d_out;

  char* ws = (char*)d_ws;
  size_t o = 0;
  auto alloc = [&](size_t b) {
    size_t p = o;
    o += (b + 255) & ~(size_t)255;
    return p;
  };
  size_t deg_o = alloc(NN * 4);                 // written by binfill (no pre-zero)
  size_t gsum_o = alloc((size_t)NG * HID * 4);
  size_t pos_o = alloc((NG + 1) * 4);
  size_t hist_o = alloc((size_t)NBIN * 256 * 4);
  size_t gbb_o = alloc((NBIN + 1) * 4);
  size_t part_o = alloc((size_t)NE * 8);        // bin-partitioned edges
  size_t bkt_o = alloc((size_t)NN * CAP * 4);   // packed-u32 bucketed CSR
  size_t h1_o = alloc((size_t)NN * HID * 2);
  size_t x1_o = alloc((size_t)NN * HID * 2);
  size_t h2_o = alloc((size_t)NN * HID * 2);
  size_t whi_o = alloc((size_t)4 * 16384 * 2);  // f16, 4 matrices frag-linear

  int* deg = (int*)(ws + deg_o);
  float* gsum = (float*)(ws + gsum_o);
  int* pos = (int*)(ws + pos_o);
  int* hist = (int*)(ws + hist_o);
  int* gbinbase = (int*)(ws + gbb_o);
  int2* part = (int2*)(ws + part_o);
  unsigned* bkt = (unsigned*)(ws + bkt_o);
  _Float16* h1 = (_Float16*)(ws + h1_o);
  _Float16* x1h = (_Float16*)(ws + x1_o);
  _Float16* h2 = (_Float16*)(ws + h2_o);
  _Float16* whi = (_Float16*)(ws + whi_o);

  // 8 dispatches, zero global atomics in the CSR build
  k_prep<<<492, 256, 0, stream>>>(batch, gsum, pos, W1a, W1b, W2a, W2b, whi,
                                  dst, hist);
  k_scatter<<<256, 256, 0, stream>>>(src, dst, ew, hist, gbinbase, part);
  k_binfill<<<NBIN, 256, 0, stream>>>(part, gbinbase, bkt, deg);

  k_layer1<<<NN / 4, 256, 0, stream>>>(nw, bkt, deg, Wn, bn, We, be, h1);

  size_t smem = (size_t)TR * ASTRH * 2 + TR * 4;  // 17,664 B -> up to 6 blocks/CU
  const int mlpBlocks = (NN + TR - 1) / TR;  // 782
  k_mlp<0><<<mlpBlocks, 256, smem, stream>>>(h1, whi, b1a, whi + 16384, b1b,
                                             x1h, nullptr, nullptr);

  k_layer2<<<NN / 8, 256, 0, stream>>>(x1h, bkt, deg, We, be, h2);

  k_mlp<1><<<mlpBlocks, 256, smem, stream>>>(h2, whi + 2 * 16384, b2a,
                                             whi + 3 * 16384, b2b,
                                             nullptr, batch, gsum);

  k_final<<<NG, HID, 0, stream>>>(gsum, pos, Wm1, bm1, Wm2, bm2, out);
}